// Round 5
// baseline (289.092 us; speedup 1.0000x reference)
//
#include <hip/hip_runtime.h>
#include <cmath>

#define BB 4
#define CC 128
#define HH 64
#define WW 64
#define SP 4096   // H*W
#define NG 32     // groups
#define TT 64     // attention uv-tile width
#define NS 4      // attention uv split factor
#define PSZ ((size_t)BB * SP * CC)   // partial tensor elements

typedef __bf16 bf16x8 __attribute__((ext_vector_type(8)));
typedef __bf16 bf16x4 __attribute__((ext_vector_type(4)));
typedef float  f32x4  __attribute__((ext_vector_type(4)));

__device__ __forceinline__ float silu_f(float v) {
    return v / (1.f + __expf(-v));
}

__device__ __forceinline__ float fast_exp2(float x) {
    return exp2f(x);   // v_exp_f32
}

// DPP-based add of lane^mask partner within each row of 16 (VALU pipe, not LDS).
template<int CTRL>
__device__ __forceinline__ float dpp_add(float v) {
    int m = __builtin_amdgcn_update_dpp(0, __float_as_int(v), CTRL, 0xF, 0xF, true);
    return v + __int_as_float(m);
}
// 16-lane sum (over lane bits 0..3): xor1, xor2 (quad_perm), then after quads are
// uniform, row_half_mirror (= +quad^1) and row_mirror (= +quad^3) complete the sum.
__device__ __forceinline__ float row16_sum(float v) {
    v = dpp_add<0xB1>(v);    // quad_perm [1,0,3,2]  : + lane^1
    v = dpp_add<0x4E>(v);    // quad_perm [2,3,0,1]  : + lane^2
    v = dpp_add<0x141>(v);   // row_half_mirror      : + other quad in half
    v = dpp_add<0x140>(v);   // row_mirror           : + other half of row
    return v;
}

// ================= merged prep kernel (slim LDS) =================
__global__ __launch_bounds__(256) void prep_kernel(
    const float* __restrict__ x, const float* __restrict__ gn1s,
    const float* __restrict__ gn1b, __bf16* __restrict__ aT,
    const float* __restrict__ c1w, const float* __restrict__ c2w,
    __bf16* __restrict__ wt,
    const float* __restrict__ t, const float* __restrict__ mlpw,
    const float* __restrict__ mlpb, float* __restrict__ tembw,
    const float* __restrict__ cond, const float* __restrict__ cw,
    const float* __restrict__ cb, __bf16* __restrict__ cmT,
    __bf16* __restrict__ cm2)
{
    __shared__ __align__(16) char pool[18432];
    __shared__ float rs[4], rs2[4], mean_s, inv_s;
    const int blk = blockIdx.x;
    const int tid = threadIdx.x;

    if (blk < 128) {
        // ---- GN1 two-pass ----
        const int b = blk >> 5, g = blk & 31;
        const float* p = x + (size_t)blk * 16384;
        float s = 0.f, s2 = 0.f;
        for (int it = 0; it < 16; ++it) {
            int q = it * 256 + tid;
            float4 v = *(const float4*)&p[q * 4];
            s += v.x + v.y + v.z + v.w;
            s2 += v.x * v.x + v.y * v.y + v.z * v.z + v.w * v.w;
        }
        #pragma unroll
        for (int off = 32; off >= 1; off >>= 1) {
            s  += __shfl_down(s,  off, 64);
            s2 += __shfl_down(s2, off, 64);
        }
        const int wid = tid >> 6;
        if ((tid & 63) == 0) { rs[wid] = s; rs2[wid] = s2; }
        __syncthreads();
        if (tid == 0) {
            float S = rs[0] + rs[1] + rs[2] + rs[3];
            float S2 = rs2[0] + rs2[1] + rs2[2] + rs2[3];
            float m = S * (1.f / 16384.f);
            float var = S2 * (1.f / 16384.f) - m * m;
            mean_s = m;
            inv_s = rsqrtf(var + 1e-5f);
        }
        __syncthreads();
        const float m = mean_s, inv = inv_s;
        float sc[4], bi[4];
        #pragma unroll
        for (int j = 0; j < 4; ++j) { sc[j] = gn1s[g * 4 + j]; bi[j] = gn1b[g * 4 + j]; }
        for (int it = 0; it < 16; ++it) {
            int pp = it * 256 + tid;
            bf16x4 o;
            #pragma unroll
            for (int j = 0; j < 4; ++j)
                o[j] = (__bf16)silu_f((p[j * 4096 + pp] - m) * inv * sc[j] + bi[j]);
            *(bf16x4*)&aT[((size_t)(b * SP + pp)) * CC + g * 4] = o;
        }
    } else if (blk < 146) {
        // ---- weight transpose ----
        const int idx = blk - 128;
        const int wsel = idx / 9, tap = idx % 9;
        const float* src = wsel ? c2w : c1w;
        __bf16* dst = wt + (size_t)wsel * 9 * 16384 + (size_t)tap * 16384;
        for (int it = 0; it < 64; ++it) {
            int q = it * 256 + tid;
            dst[q] = (__bf16)src[(size_t)q * 9 + tap];
        }
    } else if (blk < 154) {
        // ---- temb MLP ----
        const int cog = blk - 146;
        float* st = (float*)pool;
        for (int it = 0; it < 8; ++it) {
            int q = it * 256 + tid;
            st[q] = silu_f(t[q]);
        }
        __syncthreads();
        const int col = tid >> 4, seg = tid & 15;
        const float* wr = mlpw + (size_t)(cog * 16 + col) * 512 + seg * 32;
        float acc[4] = {0.f, 0.f, 0.f, 0.f};
        #pragma unroll
        for (int k8 = 0; k8 < 8; ++k8) {
            float4 wv = *(const float4*)&wr[k8 * 4];
            #pragma unroll
            for (int j = 0; j < 4; ++j) {
                int k = seg * 32 + k8 * 4 + j;
                float w4 = (&wv.x)[j];
                acc[0] += st[0 * 512 + k] * w4;
                acc[1] += st[1 * 512 + k] * w4;
                acc[2] += st[2 * 512 + k] * w4;
                acc[3] += st[3 * 512 + k] * w4;
            }
        }
        #pragma unroll
        for (int o = 1; o < 16; o <<= 1) {
            #pragma unroll
            for (int b4 = 0; b4 < 4; ++b4)
                acc[b4] += __shfl_xor(acc[b4], o, 64);
        }
        if (seg == 0) {
            float bv = mlpb[cog * 16 + col];
            #pragma unroll
            for (int b4 = 0; b4 < 4; ++b4)
                tembw[b4 * 128 + cog * 16 + col] = acc[b4] + bv;
        }
    } else {
        // ---- 1x1 conv MFMA ----
        const int pblk = blk - 154;
        const int b = pblk >> 6;
        const int p0 = (pblk & 63) * 64;
        const int l = tid & 63, wv = tid >> 6;
        const int l15 = l & 15, l4 = l >> 4;
        const int mB = wv * 32;

        __bf16* XT = (__bf16*)pool;

        for (int it = 0; it < 32; ++it) {
            int q = it * 256 + tid;
            float v = cond[((size_t)(b * CC + (q >> 6))) * SP + p0 + (q & 63)];
            XT[(q & 63) * 136 + (q >> 6)] = (__bf16)v;
        }
        __syncthreads();

        f32x4 acc[2][4];
        #pragma unroll
        for (int mb = 0; mb < 2; ++mb)
            #pragma unroll
            for (int nt = 0; nt < 4; ++nt) acc[mb][nt] = (f32x4){0.f, 0.f, 0.f, 0.f};

        #pragma unroll
        for (int ks = 0; ks < 4; ++ks) {
            bf16x8 bfr[4];
            #pragma unroll
            for (int nt = 0; nt < 4; ++nt)
                bfr[nt] = *(const bf16x8*)&XT[(nt * 16 + l15) * 136 + ks * 32 + l4 * 8];
            #pragma unroll
            for (int mb = 0; mb < 2; ++mb) {
                const float* wrow = cw + (size_t)(mB + mb * 16 + l15) * 128 + ks * 32 + l4 * 8;
                float4 wa = *(const float4*)wrow;
                float4 wb4 = *(const float4*)(wrow + 4);
                bf16x8 afr;
                afr[0] = (__bf16)wa.x; afr[1] = (__bf16)wa.y;
                afr[2] = (__bf16)wa.z; afr[3] = (__bf16)wa.w;
                afr[4] = (__bf16)wb4.x; afr[5] = (__bf16)wb4.y;
                afr[6] = (__bf16)wb4.z; afr[7] = (__bf16)wb4.w;
                #pragma unroll
                for (int nt = 0; nt < 4; ++nt)
                    acc[mb][nt] = __builtin_amdgcn_mfma_f32_16x16x32_bf16(afr, bfr[nt], acc[mb][nt], 0, 0, 0);
            }
        }

        // scale = log2(e)/sqrt(128): folds the softmax temperature AND the
        // exp->exp2 conversion into the attention K operand (cmT is only ever
        // consumed as the QK^T A-operand in attn_kernel).
        const float scl = 0.12751743f;
        #pragma unroll
        for (int mb = 0; mb < 2; ++mb) {
            int co0 = mB + mb * 16 + l4 * 4;
            float bv[4];
            #pragma unroll
            for (int r = 0; r < 4; ++r) bv[r] = cb[co0 + r];
            #pragma unroll
            for (int nt = 0; nt < 4; ++nt) {
                int p = p0 + nt * 16 + l15;
                bf16x4 o;
                #pragma unroll
                for (int r = 0; r < 4; ++r)
                    o[r] = (__bf16)((acc[mb][nt][r] + bv[r]) * scl);
                *(bf16x4*)&cmT[((size_t)(b * SP + p)) * CC + co0] = o;
            }
        }
        __syncthreads();
        __bf16* O2 = (__bf16*)pool;
        #pragma unroll
        for (int mb = 0; mb < 2; ++mb) {
            int co0 = mB + mb * 16 + l4 * 4;
            #pragma unroll
            for (int r = 0; r < 4; ++r) {
                float bv = cb[co0 + r];
                #pragma unroll
                for (int nt = 0; nt < 4; ++nt)
                    O2[(co0 + r) * 72 + nt * 16 + l15] = (__bf16)(acc[mb][nt][r] + bv);
            }
        }
        __syncthreads();
        #pragma unroll
        for (int it = 0; it < 4; ++it) {
            int q = it * 256 + tid;
            int co = q >> 3, pc = q & 7;
            *(bf16x8*)&cm2[((size_t)(b * CC + co)) * SP + p0 + pc * 8] =
                *(const bf16x8*)&O2[co * 72 + pc * 8];
        }
    }
}

// ---------------- 3x3 conv: optional fused GN+SiLU on staging ----------------
template<bool FUSE_TEMB, bool OUT_CF, bool FUSE_GN>
__global__ __launch_bounds__(256, 4) void conv_mfma_kernel(
    const __bf16* __restrict__ inT, const __bf16* __restrict__ wt,
    const float* __restrict__ bias, const float* __restrict__ temb,
    const float* __restrict__ resid, __bf16* __restrict__ outT,
    float* __restrict__ outF, const float* __restrict__ gstat,
    const float* __restrict__ gn_s, const float* __restrict__ gn_b)
{
    const int y   = blockIdx.x >> 2;
    const int xh2 = (blockIdx.x >> 1) & 1;
    const int coh = blockIdx.x & 1;
    const int x0  = xh2 * 32;
    const int b   = blockIdx.y;
    const int tid = threadIdx.x;
    const int l = tid & 63, wv = tid >> 6;
    const int l15 = l & 15, l4 = l >> 4;
    const int co_w = coh * 64 + wv * 16;

    __shared__ __bf16 inS[3 * 16 * 34 * 8];   // 26 KB
    __shared__ float af[128], bfp[128];

    if (FUSE_GN) {
        if (tid < 128) {
            int g = tid >> 2;
            float S = gstat[(b * NG + g) * 2], S2 = gstat[(b * NG + g) * 2 + 1];
            float m = S * (1.f / 16384.f);
            float var = S2 * (1.f / 16384.f) - m * m;
            float inv = rsqrtf(var + 1e-5f);
            float a = inv * gn_s[tid];
            af[tid] = a;
            bfp[tid] = gn_b[tid] - m * a;
        }
        __syncthreads();
    }

    const __bf16* inTb = inT + (size_t)b * SP * CC;
    for (int q = tid; q < 3 * 34 * 16; q += 256) {
        int cc = q & 15;
        int t2 = q >> 4;
        int xs = t2 % 34;
        int r  = t2 / 34;
        int yy = y + r - 1;
        int xg = x0 + xs - 1;
        bf16x8 v;
        if (((unsigned)yy < 64u) && ((unsigned)xg < 64u)) {
            bf16x8 raw = *(const bf16x8*)&inTb[((size_t)(yy * 64 + xg)) * CC + cc * 8];
            if (FUSE_GN) {
                #pragma unroll
                for (int j = 0; j < 8; ++j) {
                    int c = cc * 8 + j;
                    v[j] = (__bf16)silu_f((float)raw[j] * af[c] + bfp[c]);
                }
            } else {
                v = raw;
            }
        } else {
            #pragma unroll
            for (int j = 0; j < 8; ++j) v[j] = (__bf16)0.f;
        }
        *(bf16x8*)&inS[((r * 16 + cc) * 34 + xs) * 8] = v;
    }
    __syncthreads();

    f32x4 acc[2];
    acc[0] = (f32x4){0.f, 0.f, 0.f, 0.f};
    acc[1] = (f32x4){0.f, 0.f, 0.f, 0.f};

    const __bf16* wp = wt + (size_t)(co_w + l15) * 128 + l4 * 8;
    bf16x8 wb[2][4];
    #pragma unroll
    for (int ks = 0; ks < 4; ++ks)
        wb[0][ks] = *(const bf16x8*)(wp + ks * 32);

    #pragma unroll
    for (int tap = 0; tap < 9; ++tap) {
        const int cur = tap & 1, nxt = cur ^ 1;
        if (tap < 8) {
            #pragma unroll
            for (int ks = 0; ks < 4; ++ks)
                wb[nxt][ks] = *(const bf16x8*)(wp + (tap + 1) * 16384 + ks * 32);
        }
        const int rr = tap / 3, dx = tap % 3;
        #pragma unroll
        for (int ks = 0; ks < 4; ++ks) {
            const __bf16* rb = &inS[((rr * 16 + ks * 4 + l4) * 34) * 8];
            bf16x8 b0 = *(const bf16x8*)&rb[(dx + l15) * 8];
            bf16x8 b1 = *(const bf16x8*)&rb[(16 + dx + l15) * 8];
            acc[0] = __builtin_amdgcn_mfma_f32_16x16x32_bf16(wb[cur][ks], b0, acc[0], 0, 0, 0);
            acc[1] = __builtin_amdgcn_mfma_f32_16x16x32_bf16(wb[cur][ks], b1, acc[1], 0, 0, 0);
        }
    }

    if (OUT_CF) {
        #pragma unroll
        for (int r = 0; r < 4; ++r) {
            int co = co_w + l4 * 4 + r;
            float bv = bias[co];
            #pragma unroll
            for (int nb = 0; nb < 2; ++nb) {
                int p = y * 64 + x0 + nb * 16 + l15;
                size_t o = ((size_t)(b * CC + co)) * SP + p;
                outF[o] = acc[nb][r] + bv + resid[o];
            }
        }
    } else {
        int co0 = co_w + l4 * 4;
        float bv[4];
        #pragma unroll
        for (int r = 0; r < 4; ++r)
            bv[r] = bias[co0 + r] + (FUSE_TEMB ? temb[b * CC + co0 + r] : 0.f);
        #pragma unroll
        for (int nb = 0; nb < 2; ++nb) {
            int p = y * 64 + x0 + nb * 16 + l15;
            bf16x4 o;
            #pragma unroll
            for (int r = 0; r < 4; ++r)
                o[r] = (__bf16)(acc[nb][r] + bv[r]);
            *(bf16x4*)&outT[((size_t)(b * SP + p)) * CC + co0] = o;
        }
    }
}

// ---------------- fused cross-attention v10 ----------------
// v9 structure (NS=4, single-buffered ct2, LDS 36.9KB) with
// launch_bounds(256,3): v7/v9's (256,2) gave the allocator a 256-reg
// (VGPR+AGPR unified) budget -> total alloc >168 -> hardware pinned 2
// waves/SIMD (occupancy 19% in BOTH, LDS irrelevant). v8's (256,4) = 128-reg
// budget spilled to scratch (FETCH 528MB). (256,3) = 168-reg budget: live
// state ~146 regs fits -> no spill, 3 waves/SIMD -> 3 blocks/CU (LDS 3x36.9
// = 110.6KB < 160KB).
#define CT2 72    // ct2 row stride (bf16)
#define PBS 72    // Pb row stride (bf16)
// pool: ct2 18432 B (single), Pb[2] 2x9216 B = 18432 -> 36864 B
#define POOL_BYTES 36864

__global__ __launch_bounds__(256, 3) void attn_kernel(
    const __bf16* __restrict__ h1T, const __bf16* __restrict__ cmT,
    const __bf16* __restrict__ cm2,
    __bf16* __restrict__ pp0, __bf16* __restrict__ pp1,
    __bf16* __restrict__ pp2, __bf16* __restrict__ pp3)
{
    const int w = blockIdx.x;
    const int b = blockIdx.y;
    const int s = blockIdx.z;
    const int tid = threadIdx.x;
    const int wl = tid >> 6;
    const int l = tid & 63, l15 = l & 15, l4 = l >> 4;
    const int hB = (wl & 1) * 32;
    const int cB = (wl >> 1) * 64;

    __shared__ __align__(16) char pool[POOL_BYTES];
    __bf16* ct2p = (__bf16*)pool;               // single buffer, 128 x CT2
    __bf16* Pbp  = (__bf16*)(pool + 18432);     // 2 buffers of 4608 elems
    __bf16* Otr  = (__bf16*)pool;               // epilogue alias

    const __bf16* h1Tb = h1T + (size_t)b * SP * CC;
    const __bf16* cmTb = cmT + (size_t)b * SP * CC;
    const __bf16* cm2b = cm2 + (size_t)b * CC * SP;

    bf16x8 hfr[4][4];
    #pragma unroll
    for (int nt = 0; nt < 4; ++nt)
        #pragma unroll
        for (int ks = 0; ks < 4; ++ks)
            hfr[nt][ks] = *(const bf16x8*)&h1Tb[((size_t)((nt * 16 + l15) * WW + w)) * CC + ks * 32 + l4 * 8];

    f32x4 acc2[2][4];
    #pragma unroll
    for (int mb = 0; mb < 2; ++mb)
        #pragma unroll
        for (int nt = 0; nt < 4; ++nt) acc2[mb][nt] = (f32x4){0.f, 0.f, 0.f, 0.f};

    const int sc = tid >> 3;
    const int stc = tid & 7;

    // prologue: stage ct2 (tile 0), produce Pb[0] (tile 0)
    {
        const int uv0 = s * TT;
        #pragma unroll
        for (int it = 0; it < 4; ++it) {
            int c = it * 32 + sc;
            *(bf16x8*)&ct2p[c * CT2 + stc * 8] =
                *(const bf16x8*)&cm2b[(size_t)c * SP + uv0 + stc * 8];
        }
        const __bf16* arow = cmTb + (size_t)(uv0 + 16 * wl + l15) * CC;
        bf16x8 afr[4];
        #pragma unroll
        for (int ks = 0; ks < 4; ++ks) afr[ks] = *(const bf16x8*)&arow[ks * 32 + l4 * 8];
        f32x4 s1[4];
        __builtin_amdgcn_s_setprio(1);
        #pragma unroll
        for (int nt = 0; nt < 4; ++nt) {
            s1[nt] = (f32x4){0.f, 0.f, 0.f, 0.f};
            #pragma unroll
            for (int ks = 0; ks < 4; ++ks)
                s1[nt] = __builtin_amdgcn_mfma_f32_16x16x32_bf16(afr[ks], hfr[nt][ks], s1[nt], 0, 0, 0);
        }
        __builtin_amdgcn_s_setprio(0);
        #pragma unroll
        for (int r = 0; r < 4; ++r) {
            float e0 = fast_exp2(s1[0][r]), e1 = fast_exp2(s1[1][r]);
            float e2 = fast_exp2(s1[2][r]), e3 = fast_exp2(s1[3][r]);
            float sm = (e0 + e1) + (e2 + e3);
            sm = row16_sum(sm);
            float ri = 1.f / sm;
            s1[0][r] = e0 * ri; s1[1][r] = e1 * ri;
            s1[2][r] = e2 * ri; s1[3][r] = e3 * ri;
        }
        #pragma unroll
        for (int nt = 0; nt < 4; ++nt) {
            bf16x4 pk;
            pk[0] = (__bf16)s1[nt][0]; pk[1] = (__bf16)s1[nt][1];
            pk[2] = (__bf16)s1[nt][2]; pk[3] = (__bf16)s1[nt][3];
            *(bf16x4*)&Pbp[(nt * 16 + l15) * PBS + 16 * wl + l4 * 4] = pk;
        }
    }

    const int NIT = SP / TT / NS;   // 16
    for (int i = 0; i < NIT; ++i) {
        const int cur = i & 1;
        __syncthreads();   // A: ct2 (tile i) + Pb[cur] complete
        // prefetch tile i+1 operands into registers
        bf16x8 st4[4];
        bf16x8 afr[4];
        if (i < NIT - 1) {
            const int uv0n = ((i + 1) * NS + s) * TT;
            #pragma unroll
            for (int it = 0; it < 4; ++it) {
                int c = it * 32 + sc;
                st4[it] = *(const bf16x8*)&cm2b[(size_t)c * SP + uv0n + stc * 8];
            }
            const __bf16* arow = cmTb + (size_t)(uv0n + 16 * wl + l15) * CC;
            #pragma unroll
            for (int ks = 0; ks < 4; ++ks) afr[ks] = *(const bf16x8*)&arow[ks * 32 + l4 * 8];
        }
        // consume tile i: mm2 from Pb[cur], ct2
        {
            const __bf16* PbR = Pbp + cur * 4608;
            bf16x8 pfr[2][2];
            #pragma unroll
            for (int mb = 0; mb < 2; ++mb)
                #pragma unroll
                for (int ks = 0; ks < 2; ++ks)
                    pfr[mb][ks] = *(const bf16x8*)&PbR[(hB + mb * 16 + l15) * PBS + ks * 32 + l4 * 8];
            bf16x8 bfr[4][2];
            #pragma unroll
            for (int nt = 0; nt < 4; ++nt)
                #pragma unroll
                for (int ks = 0; ks < 2; ++ks)
                    bfr[nt][ks] = *(const bf16x8*)&ct2p[(cB + nt * 16 + l15) * CT2 + ks * 32 + l4 * 8];
            __builtin_amdgcn_s_setprio(1);
            #pragma unroll
            for (int mb = 0; mb < 2; ++mb)
                #pragma unroll
                for (int nt = 0; nt < 4; ++nt)
                    #pragma unroll
                    for (int ks = 0; ks < 2; ++ks)
                        acc2[mb][nt] = __builtin_amdgcn_mfma_f32_16x16x32_bf16(
                            pfr[mb][ks], bfr[nt][ks], acc2[mb][nt], 0, 0, 0);
            __builtin_amdgcn_s_setprio(0);
        }
        // produce P for tile i+1 into the other Pb buffer (registers only)
        if (i < NIT - 1) {
            f32x4 s1[4];
            __builtin_amdgcn_s_setprio(1);
            #pragma unroll
            for (int nt = 0; nt < 4; ++nt) {
                s1[nt] = (f32x4){0.f, 0.f, 0.f, 0.f};
                #pragma unroll
                for (int ks = 0; ks < 4; ++ks)
                    s1[nt] = __builtin_amdgcn_mfma_f32_16x16x32_bf16(afr[ks], hfr[nt][ks], s1[nt], 0, 0, 0);
            }
            __builtin_amdgcn_s_setprio(0);
            #pragma unroll
            for (int r = 0; r < 4; ++r) {
                float e0 = fast_exp2(s1[0][r]), e1 = fast_exp2(s1[1][r]);
                float e2 = fast_exp2(s1[2][r]), e3 = fast_exp2(s1[3][r]);
                float sm = (e0 + e1) + (e2 + e3);
                sm = row16_sum(sm);
                float ri = 1.f / sm;
                s1[0][r] = e0 * ri; s1[1][r] = e1 * ri;
                s1[2][r] = e2 * ri; s1[3][r] = e3 * ri;
            }
            __bf16* PbW = Pbp + (cur ^ 1) * 4608;
            #pragma unroll
            for (int nt = 0; nt < 4; ++nt) {
                bf16x4 pk;
                pk[0] = (__bf16)s1[nt][0]; pk[1] = (__bf16)s1[nt][1];
                pk[2] = (__bf16)s1[nt][2]; pk[3] = (__bf16)s1[nt][3];
                *(bf16x4*)&PbW[(nt * 16 + l15) * PBS + 16 * wl + l4 * 4] = pk;
            }
        }
        __syncthreads();   // B: all waves done reading ct2 (tile i)
        // stage ct2 tile i+1 (single buffer, safe after B)
        if (i < NIT - 1) {
            #pragma unroll
            for (int it = 0; it < 4; ++it) {
                int c = it * 32 + sc;
                *(bf16x8*)&ct2p[c * CT2 + stc * 8] = st4[it];
            }
        }
    }

    __syncthreads();
    #pragma unroll
    for (int mb = 0; mb < 2; ++mb)
        #pragma unroll
        for (int nt = 0; nt < 4; ++nt)
            #pragma unroll
            for (int r = 0; r < 4; ++r)
                Otr[(hB + mb * 16 + l4 * 4 + r) * 136 + cB + nt * 16 + l15] =
                    (__bf16)acc2[mb][nt][r];
    __syncthreads();
    __bf16* pO = (s == 0) ? pp0 : (s == 1) ? pp1 : (s == 2) ? pp2 : pp3;
    #pragma unroll
    for (int it = 0; it < 4; ++it) {
        int q = it * 256 + tid;
        int h = q >> 4, cc = q & 15;
        *(bf16x8*)&pO[((size_t)(b * SP + h * WW + w)) * CC + cc * 8] =
            *(const bf16x8*)&Otr[h * 136 + cc * 8];
    }
}

// ---------------- GN2 stats: h2 -> h2T bf16 + atomic group sums ----------------
__global__ __launch_bounds__(256) void gn2_stats_kernel(
    const __bf16* __restrict__ h1T,
    const __bf16* __restrict__ pp0, const __bf16* __restrict__ pp1,
    const __bf16* __restrict__ pp2, const __bf16* __restrict__ pp3,
    const int* __restrict__ aim, const float* __restrict__ emb,
    __bf16* __restrict__ h2T, float* __restrict__ gstat)
{
    const int pb = blockIdx.x, b = blockIdx.y;
    const int tid = threadIdx.x;
    const int c4 = tid & 31;
    const float4 ev = *(const float4*)&emb[aim[b] * CC + c4 * 4];
    float s = 0.f, s2 = 0.f;
    for (int it = 0; it < 8; ++it) {
        int prow = it * 8 + (tid >> 5);
        size_t base = ((size_t)(b * SP + pb * 64 + prow)) * CC + c4 * 4;
        bf16x4 hv = *(const bf16x4*)&h1T[base];
        float v0 = (float)hv[0] + ev.x;
        float v1 = (float)hv[1] + ev.y;
        float v2 = (float)hv[2] + ev.z;
        float v3 = (float)hv[3] + ev.w;
        bf16x4 a0 = *(const bf16x4*)&pp0[base];
        bf16x4 a1 = *(const bf16x4*)&pp1[base];
        bf16x4 a2 = *(const bf16x4*)&pp2[base];
        bf16x4 a3 = *(const bf16x4*)&pp3[base];
        v0 += (float)a0[0] + (float)a1[0] + (float)a2[0] + (float)a3[0];
        v1 += (float)a0[1] + (float)a1[1] + (float)a2[1] + (float)a3[1];
        v2 += (float)a0[2] + (float)a1[2] + (float)a2[2] + (float)a3[2];
        v3 += (float)a0[3] + (float)a1[3] + (float)a2[3] + (float)a3[3];
        bf16x4 o;
        o[0] = (__bf16)v0; o[1] = (__bf16)v1;
        o[2] = (__bf16)v2; o[3] = (__bf16)v3;
        *(bf16x4*)&h2T[base] = o;
        s += v0 + v1 + v2 + v3;
        s2 += v0 * v0 + v1 * v1 + v2 * v2 + v3 * v3;
    }
    s  += __shfl_down(s,  32, 64);
    s2 += __shfl_down(s2, 32, 64);
    __shared__ float ls[4][32][2];
    const int wv = tid >> 6, ll = tid & 63;
    if (ll < 32) { ls[wv][ll][0] = s; ls[wv][ll][1] = s2; }
    __syncthreads();
    if (tid < 32) {
        float S = ls[0][tid][0] + ls[1][tid][0] + ls[2][tid][0] + ls[3][tid][0];
        float S2 = ls[0][tid][1] + ls[1][tid][1] + ls[2][tid][1] + ls[3][tid][1];
        atomicAdd(&gstat[(b * NG + tid) * 2], S);
        atomicAdd(&gstat[(b * NG + tid) * 2 + 1], S2);
    }
}

extern "C" void kernel_launch(void* const* d_in, const int* in_sizes, int n_in,
                              void* d_out, int out_size, void* d_ws, size_t ws_size,
                              hipStream_t stream)
{
    const float* x     = (const float*)d_in[0];
    const float* t     = (const float*)d_in[1];
    const int*   aim   = (const int*)  d_in[2];
    const float* cond  = (const float*)d_in[3];
    const float* gn1s  = (const float*)d_in[4];
    const float* gn1b  = (const float*)d_in[5];
    const float* c1w   = (const float*)d_in[6];
    const float* c1b   = (const float*)d_in[7];
    const float* mlpw  = (const float*)d_in[8];
    const float* mlpb  = (const float*)d_in[9];
    const float* cw    = (const float*)d_in[10];
    const float* cb    = (const float*)d_in[11];
    const float* gn2s  = (const float*)d_in[12];
    const float* gn2b  = (const float*)d_in[13];
    const float* c2w   = (const float*)d_in[14];
    const float* c2b   = (const float*)d_in[15];
    const float* emb   = (const float*)d_in[16];
    float* out = (float*)d_out;
    float* ws = (float*)d_ws;

    // float-offset workspace map
    __bf16* aT    = (__bf16*)ws;                  // [0, 1048576)
    __bf16* h1T   = (__bf16*)(ws + 1048576);
    __bf16* cmT   = (__bf16*)(ws + 2097152);      // h2T after attn
    __bf16* cm2   = (__bf16*)(ws + 3145728);
    __bf16* parts = (__bf16*)(ws + 4194304);      // partials 0,1
    __bf16* wt    = (__bf16*)(ws + 6291456);
    float*  tembw = ws + 6438912;
    float*  gstat = ws + 6439424;                 // 256 floats
    __bf16* h2T   = cmT;
    // partial 2 reuses aT (dead after conv1); partial 3 reuses out
    // (out is only written by the final conv2, which runs after gn2_stats).
    __bf16* part2 = aT;
    __bf16* part3 = (__bf16*)out;

    prep_kernel<<<dim3(410), dim3(256), 0, stream>>>(
        x, gn1s, gn1b, aT, c1w, c2w, wt, t, mlpw, mlpb, tembw,
        cond, cw, cb, cmT, cm2);
    hipMemsetAsync(gstat, 0, 256 * sizeof(float), stream);
    conv_mfma_kernel<true, false, false><<<dim3(256, BB), dim3(256), 0, stream>>>(
        aT, wt, c1b, tembw, nullptr, h1T, nullptr, nullptr, nullptr, nullptr);
    attn_kernel<<<dim3(WW, BB, NS), dim3(256), 0, stream>>>(
        h1T, cmT, cm2, parts, parts + PSZ, part2, part3);
    gn2_stats_kernel<<<dim3(64, BB), dim3(256), 0, stream>>>(
        h1T, parts, parts + PSZ, part2, part3, aim, emb, h2T, gstat);
    conv_mfma_kernel<false, true, true><<<dim3(256, BB), dim3(256), 0, stream>>>(
        h2T, wt + (size_t)9 * 16384, c2b, nullptr, x, nullptr, out, gstat, gn2s, gn2b);
}

// Round 6
// 225.880 us; speedup vs baseline: 1.2798x; 1.2798x over previous
//
#include <hip/hip_runtime.h>
#include <cmath>

#define BB 4
#define CC 128
#define HH 64
#define WW 64
#define SP 4096   // H*W
#define NG 32     // groups
#define TT 64     // attention uv-tile width
#define NS 4      // attention uv split factor
#define PSZ ((size_t)BB * SP * CC)   // partial tensor elements

typedef __bf16 bf16x8 __attribute__((ext_vector_type(8)));
typedef __bf16 bf16x4 __attribute__((ext_vector_type(4)));
typedef float  f32x4  __attribute__((ext_vector_type(4)));

__device__ __forceinline__ float silu_f(float v) {
    return v / (1.f + __expf(-v));
}

__device__ __forceinline__ float fast_exp2(float x) {
    return exp2f(x);   // v_exp_f32
}

// DPP-based add of lane^mask partner within each row of 16 (VALU pipe, not LDS).
template<int CTRL>
__device__ __forceinline__ float dpp_add(float v) {
    int m = __builtin_amdgcn_update_dpp(0, __float_as_int(v), CTRL, 0xF, 0xF, true);
    return v + __int_as_float(m);
}
// 16-lane sum (over lane bits 0..3): xor1, xor2 (quad_perm), then after quads are
// uniform, row_half_mirror (= +quad^1) and row_mirror (= +quad^3) complete the sum.
__device__ __forceinline__ float row16_sum(float v) {
    v = dpp_add<0xB1>(v);    // quad_perm [1,0,3,2]  : + lane^1
    v = dpp_add<0x4E>(v);    // quad_perm [2,3,0,1]  : + lane^2
    v = dpp_add<0x141>(v);   // row_half_mirror      : + other quad in half
    v = dpp_add<0x140>(v);   // row_mirror           : + other half of row
    return v;
}

// ================= merged prep kernel (slim LDS) =================
__global__ __launch_bounds__(256) void prep_kernel(
    const float* __restrict__ x, const float* __restrict__ gn1s,
    const float* __restrict__ gn1b, __bf16* __restrict__ aT,
    const float* __restrict__ c1w, const float* __restrict__ c2w,
    __bf16* __restrict__ wt,
    const float* __restrict__ t, const float* __restrict__ mlpw,
    const float* __restrict__ mlpb, float* __restrict__ tembw,
    const float* __restrict__ cond, const float* __restrict__ cw,
    const float* __restrict__ cb, __bf16* __restrict__ cmT,
    __bf16* __restrict__ cm2)
{
    __shared__ __align__(16) char pool[18432];
    __shared__ float rs[4], rs2[4], mean_s, inv_s;
    const int blk = blockIdx.x;
    const int tid = threadIdx.x;

    if (blk < 128) {
        // ---- GN1 two-pass ----
        const int b = blk >> 5, g = blk & 31;
        const float* p = x + (size_t)blk * 16384;
        float s = 0.f, s2 = 0.f;
        for (int it = 0; it < 16; ++it) {
            int q = it * 256 + tid;
            float4 v = *(const float4*)&p[q * 4];
            s += v.x + v.y + v.z + v.w;
            s2 += v.x * v.x + v.y * v.y + v.z * v.z + v.w * v.w;
        }
        #pragma unroll
        for (int off = 32; off >= 1; off >>= 1) {
            s  += __shfl_down(s,  off, 64);
            s2 += __shfl_down(s2, off, 64);
        }
        const int wid = tid >> 6;
        if ((tid & 63) == 0) { rs[wid] = s; rs2[wid] = s2; }
        __syncthreads();
        if (tid == 0) {
            float S = rs[0] + rs[1] + rs[2] + rs[3];
            float S2 = rs2[0] + rs2[1] + rs2[2] + rs2[3];
            float m = S * (1.f / 16384.f);
            float var = S2 * (1.f / 16384.f) - m * m;
            mean_s = m;
            inv_s = rsqrtf(var + 1e-5f);
        }
        __syncthreads();
        const float m = mean_s, inv = inv_s;
        float sc[4], bi[4];
        #pragma unroll
        for (int j = 0; j < 4; ++j) { sc[j] = gn1s[g * 4 + j]; bi[j] = gn1b[g * 4 + j]; }
        for (int it = 0; it < 16; ++it) {
            int pp = it * 256 + tid;
            bf16x4 o;
            #pragma unroll
            for (int j = 0; j < 4; ++j)
                o[j] = (__bf16)silu_f((p[j * 4096 + pp] - m) * inv * sc[j] + bi[j]);
            *(bf16x4*)&aT[((size_t)(b * SP + pp)) * CC + g * 4] = o;
        }
    } else if (blk < 146) {
        // ---- weight transpose ----
        const int idx = blk - 128;
        const int wsel = idx / 9, tap = idx % 9;
        const float* src = wsel ? c2w : c1w;
        __bf16* dst = wt + (size_t)wsel * 9 * 16384 + (size_t)tap * 16384;
        for (int it = 0; it < 64; ++it) {
            int q = it * 256 + tid;
            dst[q] = (__bf16)src[(size_t)q * 9 + tap];
        }
    } else if (blk < 154) {
        // ---- temb MLP ----
        const int cog = blk - 146;
        float* st = (float*)pool;
        for (int it = 0; it < 8; ++it) {
            int q = it * 256 + tid;
            st[q] = silu_f(t[q]);
        }
        __syncthreads();
        const int col = tid >> 4, seg = tid & 15;
        const float* wr = mlpw + (size_t)(cog * 16 + col) * 512 + seg * 32;
        float acc[4] = {0.f, 0.f, 0.f, 0.f};
        #pragma unroll
        for (int k8 = 0; k8 < 8; ++k8) {
            float4 wv = *(const float4*)&wr[k8 * 4];
            #pragma unroll
            for (int j = 0; j < 4; ++j) {
                int k = seg * 32 + k8 * 4 + j;
                float w4 = (&wv.x)[j];
                acc[0] += st[0 * 512 + k] * w4;
                acc[1] += st[1 * 512 + k] * w4;
                acc[2] += st[2 * 512 + k] * w4;
                acc[3] += st[3 * 512 + k] * w4;
            }
        }
        #pragma unroll
        for (int o = 1; o < 16; o <<= 1) {
            #pragma unroll
            for (int b4 = 0; b4 < 4; ++b4)
                acc[b4] += __shfl_xor(acc[b4], o, 64);
        }
        if (seg == 0) {
            float bv = mlpb[cog * 16 + col];
            #pragma unroll
            for (int b4 = 0; b4 < 4; ++b4)
                tembw[b4 * 128 + cog * 16 + col] = acc[b4] + bv;
        }
    } else {
        // ---- 1x1 conv MFMA ----
        const int pblk = blk - 154;
        const int b = pblk >> 6;
        const int p0 = (pblk & 63) * 64;
        const int l = tid & 63, wv = tid >> 6;
        const int l15 = l & 15, l4 = l >> 4;
        const int mB = wv * 32;

        __bf16* XT = (__bf16*)pool;

        for (int it = 0; it < 32; ++it) {
            int q = it * 256 + tid;
            float v = cond[((size_t)(b * CC + (q >> 6))) * SP + p0 + (q & 63)];
            XT[(q & 63) * 136 + (q >> 6)] = (__bf16)v;
        }
        __syncthreads();

        f32x4 acc[2][4];
        #pragma unroll
        for (int mb = 0; mb < 2; ++mb)
            #pragma unroll
            for (int nt = 0; nt < 4; ++nt) acc[mb][nt] = (f32x4){0.f, 0.f, 0.f, 0.f};

        #pragma unroll
        for (int ks = 0; ks < 4; ++ks) {
            bf16x8 bfr[4];
            #pragma unroll
            for (int nt = 0; nt < 4; ++nt)
                bfr[nt] = *(const bf16x8*)&XT[(nt * 16 + l15) * 136 + ks * 32 + l4 * 8];
            #pragma unroll
            for (int mb = 0; mb < 2; ++mb) {
                const float* wrow = cw + (size_t)(mB + mb * 16 + l15) * 128 + ks * 32 + l4 * 8;
                float4 wa = *(const float4*)wrow;
                float4 wb4 = *(const float4*)(wrow + 4);
                bf16x8 afr;
                afr[0] = (__bf16)wa.x; afr[1] = (__bf16)wa.y;
                afr[2] = (__bf16)wa.z; afr[3] = (__bf16)wa.w;
                afr[4] = (__bf16)wb4.x; afr[5] = (__bf16)wb4.y;
                afr[6] = (__bf16)wb4.z; afr[7] = (__bf16)wb4.w;
                #pragma unroll
                for (int nt = 0; nt < 4; ++nt)
                    acc[mb][nt] = __builtin_amdgcn_mfma_f32_16x16x32_bf16(afr, bfr[nt], acc[mb][nt], 0, 0, 0);
            }
        }

        // scale = log2(e)/sqrt(128): folds the softmax temperature AND the
        // exp->exp2 conversion into the attention K operand (cmT is only ever
        // consumed as the QK^T A-operand in attn_kernel).
        const float scl = 0.12751743f;
        #pragma unroll
        for (int mb = 0; mb < 2; ++mb) {
            int co0 = mB + mb * 16 + l4 * 4;
            float bv[4];
            #pragma unroll
            for (int r = 0; r < 4; ++r) bv[r] = cb[co0 + r];
            #pragma unroll
            for (int nt = 0; nt < 4; ++nt) {
                int p = p0 + nt * 16 + l15;
                bf16x4 o;
                #pragma unroll
                for (int r = 0; r < 4; ++r)
                    o[r] = (__bf16)((acc[mb][nt][r] + bv[r]) * scl);
                *(bf16x4*)&cmT[((size_t)(b * SP + p)) * CC + co0] = o;
            }
        }
        __syncthreads();
        __bf16* O2 = (__bf16*)pool;
        #pragma unroll
        for (int mb = 0; mb < 2; ++mb) {
            int co0 = mB + mb * 16 + l4 * 4;
            #pragma unroll
            for (int r = 0; r < 4; ++r) {
                float bv = cb[co0 + r];
                #pragma unroll
                for (int nt = 0; nt < 4; ++nt)
                    O2[(co0 + r) * 72 + nt * 16 + l15] = (__bf16)(acc[mb][nt][r] + bv);
            }
        }
        __syncthreads();
        #pragma unroll
        for (int it = 0; it < 4; ++it) {
            int q = it * 256 + tid;
            int co = q >> 3, pc = q & 7;
            *(bf16x8*)&cm2[((size_t)(b * CC + co)) * SP + p0 + pc * 8] =
                *(const bf16x8*)&O2[co * 72 + pc * 8];
        }
    }
}

// ---------------- 3x3 conv: optional fused GN+SiLU on staging ----------------
template<bool FUSE_TEMB, bool OUT_CF, bool FUSE_GN>
__global__ __launch_bounds__(256, 4) void conv_mfma_kernel(
    const __bf16* __restrict__ inT, const __bf16* __restrict__ wt,
    const float* __restrict__ bias, const float* __restrict__ temb,
    const float* __restrict__ resid, __bf16* __restrict__ outT,
    float* __restrict__ outF, const float* __restrict__ gstat,
    const float* __restrict__ gn_s, const float* __restrict__ gn_b)
{
    const int y   = blockIdx.x >> 2;
    const int xh2 = (blockIdx.x >> 1) & 1;
    const int coh = blockIdx.x & 1;
    const int x0  = xh2 * 32;
    const int b   = blockIdx.y;
    const int tid = threadIdx.x;
    const int l = tid & 63, wv = tid >> 6;
    const int l15 = l & 15, l4 = l >> 4;
    const int co_w = coh * 64 + wv * 16;

    __shared__ __bf16 inS[3 * 16 * 34 * 8];   // 26 KB
    __shared__ float af[128], bfp[128];

    if (FUSE_GN) {
        if (tid < 128) {
            int g = tid >> 2;
            float S = gstat[(b * NG + g) * 2], S2 = gstat[(b * NG + g) * 2 + 1];
            float m = S * (1.f / 16384.f);
            float var = S2 * (1.f / 16384.f) - m * m;
            float inv = rsqrtf(var + 1e-5f);
            float a = inv * gn_s[tid];
            af[tid] = a;
            bfp[tid] = gn_b[tid] - m * a;
        }
        __syncthreads();
    }

    const __bf16* inTb = inT + (size_t)b * SP * CC;
    for (int q = tid; q < 3 * 34 * 16; q += 256) {
        int cc = q & 15;
        int t2 = q >> 4;
        int xs = t2 % 34;
        int r  = t2 / 34;
        int yy = y + r - 1;
        int xg = x0 + xs - 1;
        bf16x8 v;
        if (((unsigned)yy < 64u) && ((unsigned)xg < 64u)) {
            bf16x8 raw = *(const bf16x8*)&inTb[((size_t)(yy * 64 + xg)) * CC + cc * 8];
            if (FUSE_GN) {
                #pragma unroll
                for (int j = 0; j < 8; ++j) {
                    int c = cc * 8 + j;
                    v[j] = (__bf16)silu_f((float)raw[j] * af[c] + bfp[c]);
                }
            } else {
                v = raw;
            }
        } else {
            #pragma unroll
            for (int j = 0; j < 8; ++j) v[j] = (__bf16)0.f;
        }
        *(bf16x8*)&inS[((r * 16 + cc) * 34 + xs) * 8] = v;
    }
    __syncthreads();

    f32x4 acc[2];
    acc[0] = (f32x4){0.f, 0.f, 0.f, 0.f};
    acc[1] = (f32x4){0.f, 0.f, 0.f, 0.f};

    const __bf16* wp = wt + (size_t)(co_w + l15) * 128 + l4 * 8;
    bf16x8 wb[2][4];
    #pragma unroll
    for (int ks = 0; ks < 4; ++ks)
        wb[0][ks] = *(const bf16x8*)(wp + ks * 32);

    #pragma unroll
    for (int tap = 0; tap < 9; ++tap) {
        const int cur = tap & 1, nxt = cur ^ 1;
        if (tap < 8) {
            #pragma unroll
            for (int ks = 0; ks < 4; ++ks)
                wb[nxt][ks] = *(const bf16x8*)(wp + (tap + 1) * 16384 + ks * 32);
        }
        const int rr = tap / 3, dx = tap % 3;
        #pragma unroll
        for (int ks = 0; ks < 4; ++ks) {
            const __bf16* rb = &inS[((rr * 16 + ks * 4 + l4) * 34) * 8];
            bf16x8 b0 = *(const bf16x8*)&rb[(dx + l15) * 8];
            bf16x8 b1 = *(const bf16x8*)&rb[(16 + dx + l15) * 8];
            acc[0] = __builtin_amdgcn_mfma_f32_16x16x32_bf16(wb[cur][ks], b0, acc[0], 0, 0, 0);
            acc[1] = __builtin_amdgcn_mfma_f32_16x16x32_bf16(wb[cur][ks], b1, acc[1], 0, 0, 0);
        }
    }

    if (OUT_CF) {
        #pragma unroll
        for (int r = 0; r < 4; ++r) {
            int co = co_w + l4 * 4 + r;
            float bv = bias[co];
            #pragma unroll
            for (int nb = 0; nb < 2; ++nb) {
                int p = y * 64 + x0 + nb * 16 + l15;
                size_t o = ((size_t)(b * CC + co)) * SP + p;
                outF[o] = acc[nb][r] + bv + resid[o];
            }
        }
    } else {
        int co0 = co_w + l4 * 4;
        float bv[4];
        #pragma unroll
        for (int r = 0; r < 4; ++r)
            bv[r] = bias[co0 + r] + (FUSE_TEMB ? temb[b * CC + co0 + r] : 0.f);
        #pragma unroll
        for (int nb = 0; nb < 2; ++nb) {
            int p = y * 64 + x0 + nb * 16 + l15;
            bf16x4 o;
            #pragma unroll
            for (int r = 0; r < 4; ++r)
                o[r] = (__bf16)(acc[nb][r] + bv[r]);
            *(bf16x4*)&outT[((size_t)(b * SP + p)) * CC + co0] = o;
        }
    }
}

// ---------------- fused cross-attention v11: Q in LDS ----------------
// The persistent 64-VGPR Q fragment (hfr) was the register-pressure blocker:
// 256-budget (256,2) -> no spill but 2 blocks/CU; 168-budget (256,3) -> spill
// (v10: WRITE 16->41MB); 128-budget (256,4) -> catastrophic spill (v8).
// v11 stages Q (64h x 128c bf16 = 16KB) into LDS once per block, XOR-swizzled
// (granule ^= h&7) so the per-lane-row ds_read_b128 hits the 8-lane/bank-quad
// floor (conflict-free). Peak regs ~100-130 < 168 -> (256,3) with no spill.
// LDS 16384+18432+18432 = 53248 B -> 3 blocks/CU (159.7KB of 160KB).
#define CT2 72    // ct2 row stride (bf16)
#define PBS 72    // Pb row stride (bf16)
// pool: Qs 16384 B, ct2 18432 B (single), Pb[2] 2x9216 B -> 53248 B
#define POOL_BYTES 53248

__global__ __launch_bounds__(256, 3) void attn_kernel(
    const __bf16* __restrict__ h1T, const __bf16* __restrict__ cmT,
    const __bf16* __restrict__ cm2,
    __bf16* __restrict__ pp0, __bf16* __restrict__ pp1,
    __bf16* __restrict__ pp2, __bf16* __restrict__ pp3)
{
    const int w = blockIdx.x;
    const int b = blockIdx.y;
    const int s = blockIdx.z;
    const int tid = threadIdx.x;
    const int wl = tid >> 6;
    const int l = tid & 63, l15 = l & 15, l4 = l >> 4;
    const int hB = (wl & 1) * 32;
    const int cB = (wl >> 1) * 64;

    __shared__ __align__(16) char pool[POOL_BYTES];
    __bf16* Qs   = (__bf16*)pool;               // 64 x 128, swizzled
    __bf16* ct2p = (__bf16*)(pool + 16384);     // single buffer, 128 x CT2
    __bf16* Pbp  = (__bf16*)(pool + 34816);     // 2 buffers of 4608 elems
    __bf16* Otr  = (__bf16*)pool;               // epilogue alias

    const __bf16* h1Tb = h1T + (size_t)b * SP * CC;
    const __bf16* cmTb = cmT + (size_t)b * SP * CC;
    const __bf16* cm2b = cm2 + (size_t)b * CC * SP;

    f32x4 acc2[2][4];
    #pragma unroll
    for (int mb = 0; mb < 2; ++mb)
        #pragma unroll
        for (int nt = 0; nt < 4; ++nt) acc2[mb][nt] = (f32x4){0.f, 0.f, 0.f, 0.f};

    const int sc = tid >> 3;
    const int stc = tid & 7;
    const int lsw = l15 & 7;   // read-side swizzle key (h&7 == l15&7)

    // prologue: stage Qs (swizzled) + ct2 (tile 0)
    {
        #pragma unroll
        for (int it = 0; it < 4; ++it) {
            int q = it * 256 + tid;
            int h = q >> 4, g = q & 15;
            bf16x8 v = *(const bf16x8*)&h1Tb[((size_t)(h * WW + w)) * CC + g * 8];
            *(bf16x8*)&Qs[h * 128 + (g ^ (h & 7)) * 8] = v;
        }
        const int uv0 = s * TT;
        #pragma unroll
        for (int it = 0; it < 4; ++it) {
            int c = it * 32 + sc;
            *(bf16x8*)&ct2p[c * CT2 + stc * 8] =
                *(const bf16x8*)&cm2b[(size_t)c * SP + uv0 + stc * 8];
        }
    }
    __syncthreads();   // Qs + ct2 tile0 ready

    // produce Pb[0] (tile 0): QK^T reads Q from LDS
    {
        const int uv0 = s * TT;
        const __bf16* arow = cmTb + (size_t)(uv0 + 16 * wl + l15) * CC;
        bf16x8 afr[4];
        #pragma unroll
        for (int ks = 0; ks < 4; ++ks) afr[ks] = *(const bf16x8*)&arow[ks * 32 + l4 * 8];
        f32x4 s1[4];
        #pragma unroll
        for (int nt = 0; nt < 4; ++nt) {
            bf16x8 hq[4];
            #pragma unroll
            for (int ks = 0; ks < 4; ++ks)
                hq[ks] = *(const bf16x8*)&Qs[(nt * 16 + l15) * 128 + (((ks * 4 + l4) ^ lsw)) * 8];
            s1[nt] = (f32x4){0.f, 0.f, 0.f, 0.f};
            __builtin_amdgcn_s_setprio(1);
            #pragma unroll
            for (int ks = 0; ks < 4; ++ks)
                s1[nt] = __builtin_amdgcn_mfma_f32_16x16x32_bf16(afr[ks], hq[ks], s1[nt], 0, 0, 0);
            __builtin_amdgcn_s_setprio(0);
        }
        #pragma unroll
        for (int r = 0; r < 4; ++r) {
            float e0 = fast_exp2(s1[0][r]), e1 = fast_exp2(s1[1][r]);
            float e2 = fast_exp2(s1[2][r]), e3 = fast_exp2(s1[3][r]);
            float sm = (e0 + e1) + (e2 + e3);
            sm = row16_sum(sm);
            float ri = 1.f / sm;
            s1[0][r] = e0 * ri; s1[1][r] = e1 * ri;
            s1[2][r] = e2 * ri; s1[3][r] = e3 * ri;
        }
        #pragma unroll
        for (int nt = 0; nt < 4; ++nt) {
            bf16x4 pk;
            pk[0] = (__bf16)s1[nt][0]; pk[1] = (__bf16)s1[nt][1];
            pk[2] = (__bf16)s1[nt][2]; pk[3] = (__bf16)s1[nt][3];
            *(bf16x4*)&Pbp[(nt * 16 + l15) * PBS + 16 * wl + l4 * 4] = pk;
        }
    }

    const int NIT = SP / TT / NS;   // 16
    for (int i = 0; i < NIT; ++i) {
        const int cur = i & 1;
        __syncthreads();   // A: ct2 (tile i) + Pb[cur] complete
        // prefetch tile i+1 operands into registers
        bf16x8 st4[4];
        bf16x8 afr[4];
        if (i < NIT - 1) {
            const int uv0n = ((i + 1) * NS + s) * TT;
            #pragma unroll
            for (int it = 0; it < 4; ++it) {
                int c = it * 32 + sc;
                st4[it] = *(const bf16x8*)&cm2b[(size_t)c * SP + uv0n + stc * 8];
            }
            const __bf16* arow = cmTb + (size_t)(uv0n + 16 * wl + l15) * CC;
            #pragma unroll
            for (int ks = 0; ks < 4; ++ks) afr[ks] = *(const bf16x8*)&arow[ks * 32 + l4 * 8];
        }
        // consume tile i: mm2 from Pb[cur], ct2
        {
            const __bf16* PbR = Pbp + cur * 4608;
            bf16x8 pfr[2][2];
            #pragma unroll
            for (int mb = 0; mb < 2; ++mb)
                #pragma unroll
                for (int ks = 0; ks < 2; ++ks)
                    pfr[mb][ks] = *(const bf16x8*)&PbR[(hB + mb * 16 + l15) * PBS + ks * 32 + l4 * 8];
            bf16x8 bfr[4][2];
            #pragma unroll
            for (int nt = 0; nt < 4; ++nt)
                #pragma unroll
                for (int ks = 0; ks < 2; ++ks)
                    bfr[nt][ks] = *(const bf16x8*)&ct2p[(cB + nt * 16 + l15) * CT2 + ks * 32 + l4 * 8];
            __builtin_amdgcn_s_setprio(1);
            #pragma unroll
            for (int mb = 0; mb < 2; ++mb)
                #pragma unroll
                for (int nt = 0; nt < 4; ++nt)
                    #pragma unroll
                    for (int ks = 0; ks < 2; ++ks)
                        acc2[mb][nt] = __builtin_amdgcn_mfma_f32_16x16x32_bf16(
                            pfr[mb][ks], bfr[nt][ks], acc2[mb][nt], 0, 0, 0);
            __builtin_amdgcn_s_setprio(0);
        }
        // produce P for tile i+1 into the other Pb buffer
        if (i < NIT - 1) {
            f32x4 s1[4];
            #pragma unroll
            for (int nt = 0; nt < 4; ++nt) {
                bf16x8 hq[4];
                #pragma unroll
                for (int ks = 0; ks < 4; ++ks)
                    hq[ks] = *(const bf16x8*)&Qs[(nt * 16 + l15) * 128 + (((ks * 4 + l4) ^ lsw)) * 8];
                s1[nt] = (f32x4){0.f, 0.f, 0.f, 0.f};
                __builtin_amdgcn_s_setprio(1);
                #pragma unroll
                for (int ks = 0; ks < 4; ++ks)
                    s1[nt] = __builtin_amdgcn_mfma_f32_16x16x32_bf16(afr[ks], hq[ks], s1[nt], 0, 0, 0);
                __builtin_amdgcn_s_setprio(0);
            }
            #pragma unroll
            for (int r = 0; r < 4; ++r) {
                float e0 = fast_exp2(s1[0][r]), e1 = fast_exp2(s1[1][r]);
                float e2 = fast_exp2(s1[2][r]), e3 = fast_exp2(s1[3][r]);
                float sm = (e0 + e1) + (e2 + e3);
                sm = row16_sum(sm);
                float ri = 1.f / sm;
                s1[0][r] = e0 * ri; s1[1][r] = e1 * ri;
                s1[2][r] = e2 * ri; s1[3][r] = e3 * ri;
            }
            __bf16* PbW = Pbp + (cur ^ 1) * 4608;
            #pragma unroll
            for (int nt = 0; nt < 4; ++nt) {
                bf16x4 pk;
                pk[0] = (__bf16)s1[nt][0]; pk[1] = (__bf16)s1[nt][1];
                pk[2] = (__bf16)s1[nt][2]; pk[3] = (__bf16)s1[nt][3];
                *(bf16x4*)&PbW[(nt * 16 + l15) * PBS + 16 * wl + l4 * 4] = pk;
            }
        }
        __syncthreads();   // B: all waves done reading ct2 (tile i)
        // stage ct2 tile i+1 (single buffer, safe after B)
        if (i < NIT - 1) {
            #pragma unroll
            for (int it = 0; it < 4; ++it) {
                int c = it * 32 + sc;
                *(bf16x8*)&ct2p[c * CT2 + stc * 8] = st4[it];
            }
        }
    }

    __syncthreads();
    #pragma unroll
    for (int mb = 0; mb < 2; ++mb)
        #pragma unroll
        for (int nt = 0; nt < 4; ++nt)
            #pragma unroll
            for (int r = 0; r < 4; ++r)
                Otr[(hB + mb * 16 + l4 * 4 + r) * 136 + cB + nt * 16 + l15] =
                    (__bf16)acc2[mb][nt][r];
    __syncthreads();
    __bf16* pO = (s == 0) ? pp0 : (s == 1) ? pp1 : (s == 2) ? pp2 : pp3;
    #pragma unroll
    for (int it = 0; it < 4; ++it) {
        int q = it * 256 + tid;
        int h = q >> 4, cc = q & 15;
        *(bf16x8*)&pO[((size_t)(b * SP + h * WW + w)) * CC + cc * 8] =
            *(const bf16x8*)&Otr[h * 136 + cc * 8];
    }
}

// ---------------- GN2 stats: h2 -> h2T bf16 + atomic group sums ----------------
__global__ __launch_bounds__(256) void gn2_stats_kernel(
    const __bf16* __restrict__ h1T,
    const __bf16* __restrict__ pp0, const __bf16* __restrict__ pp1,
    const __bf16* __restrict__ pp2, const __bf16* __restrict__ pp3,
    const int* __restrict__ aim, const float* __restrict__ emb,
    __bf16* __restrict__ h2T, float* __restrict__ gstat)
{
    const int pb = blockIdx.x, b = blockIdx.y;
    const int tid = threadIdx.x;
    const int c4 = tid & 31;
    const float4 ev = *(const float4*)&emb[aim[b] * CC + c4 * 4];
    float s = 0.f, s2 = 0.f;
    for (int it = 0; it < 8; ++it) {
        int prow = it * 8 + (tid >> 5);
        size_t base = ((size_t)(b * SP + pb * 64 + prow)) * CC + c4 * 4;
        bf16x4 hv = *(const bf16x4*)&h1T[base];
        float v0 = (float)hv[0] + ev.x;
        float v1 = (float)hv[1] + ev.y;
        float v2 = (float)hv[2] + ev.z;
        float v3 = (float)hv[3] + ev.w;
        bf16x4 a0 = *(const bf16x4*)&pp0[base];
        bf16x4 a1 = *(const bf16x4*)&pp1[base];
        bf16x4 a2 = *(const bf16x4*)&pp2[base];
        bf16x4 a3 = *(const bf16x4*)&pp3[base];
        v0 += (float)a0[0] + (float)a1[0] + (float)a2[0] + (float)a3[0];
        v1 += (float)a0[1] + (float)a1[1] + (float)a2[1] + (float)a3[1];
        v2 += (float)a0[2] + (float)a1[2] + (float)a2[2] + (float)a3[2];
        v3 += (float)a0[3] + (float)a1[3] + (float)a2[3] + (float)a3[3];
        bf16x4 o;
        o[0] = (__bf16)v0; o[1] = (__bf16)v1;
        o[2] = (__bf16)v2; o[3] = (__bf16)v3;
        *(bf16x4*)&h2T[base] = o;
        s += v0 + v1 + v2 + v3;
        s2 += v0 * v0 + v1 * v1 + v2 * v2 + v3 * v3;
    }
    s  += __shfl_down(s,  32, 64);
    s2 += __shfl_down(s2, 32, 64);
    __shared__ float ls[4][32][2];
    const int wv = tid >> 6, ll = tid & 63;
    if (ll < 32) { ls[wv][ll][0] = s; ls[wv][ll][1] = s2; }
    __syncthreads();
    if (tid < 32) {
        float S = ls[0][tid][0] + ls[1][tid][0] + ls[2][tid][0] + ls[3][tid][0];
        float S2 = ls[0][tid][1] + ls[1][tid][1] + ls[2][tid][1] + ls[3][tid][1];
        atomicAdd(&gstat[(b * NG + tid) * 2], S);
        atomicAdd(&gstat[(b * NG + tid) * 2 + 1], S2);
    }
}

extern "C" void kernel_launch(void* const* d_in, const int* in_sizes, int n_in,
                              void* d_out, int out_size, void* d_ws, size_t ws_size,
                              hipStream_t stream)
{
    const float* x     = (const float*)d_in[0];
    const float* t     = (const float*)d_in[1];
    const int*   aim   = (const int*)  d_in[2];
    const float* cond  = (const float*)d_in[3];
    const float* gn1s  = (const float*)d_in[4];
    const float* gn1b  = (const float*)d_in[5];
    const float* c1w   = (const float*)d_in[6];
    const float* c1b   = (const float*)d_in[7];
    const float* mlpw  = (const float*)d_in[8];
    const float* mlpb  = (const float*)d_in[9];
    const float* cw    = (const float*)d_in[10];
    const float* cb    = (const float*)d_in[11];
    const float* gn2s  = (const float*)d_in[12];
    const float* gn2b  = (const float*)d_in[13];
    const float* c2w   = (const float*)d_in[14];
    const float* c2b   = (const float*)d_in[15];
    const float* emb   = (const float*)d_in[16];
    float* out = (float*)d_out;
    float* ws = (float*)d_ws;

    // float-offset workspace map
    __bf16* aT    = (__bf16*)ws;                  // [0, 1048576)
    __bf16* h1T   = (__bf16*)(ws + 1048576);
    __bf16* cmT   = (__bf16*)(ws + 2097152);      // h2T after attn
    __bf16* cm2   = (__bf16*)(ws + 3145728);
    __bf16* parts = (__bf16*)(ws + 4194304);      // partials 0,1
    __bf16* wt    = (__bf16*)(ws + 6291456);
    float*  tembw = ws + 6438912;
    float*  gstat = ws + 6439424;                 // 256 floats
    __bf16* h2T   = cmT;
    // partial 2 reuses aT (dead after conv1); partial 3 reuses out
    // (out is only written by the final conv2, which runs after gn2_stats).
    __bf16* part2 = aT;
    __bf16* part3 = (__bf16*)out;

    prep_kernel<<<dim3(410), dim3(256), 0, stream>>>(
        x, gn1s, gn1b, aT, c1w, c2w, wt, t, mlpw, mlpb, tembw,
        cond, cw, cb, cmT, cm2);
    hipMemsetAsync(gstat, 0, 256 * sizeof(float), stream);
    conv_mfma_kernel<true, false, false><<<dim3(256, BB), dim3(256), 0, stream>>>(
        aT, wt, c1b, tembw, nullptr, h1T, nullptr, nullptr, nullptr, nullptr);
    attn_kernel<<<dim3(WW, BB, NS), dim3(256), 0, stream>>>(
        h1T, cmT, cm2, parts, parts + PSZ, part2, part3);
    gn2_stats_kernel<<<dim3(64, BB), dim3(256), 0, stream>>>(
        h1T, parts, parts + PSZ, part2, part3, aim, emb, h2T, gstat);
    conv_mfma_kernel<false, true, true><<<dim3(256, BB), dim3(256), 0, stream>>>(
        h2T, wt + (size_t)9 * 16384, c2b, nullptr, x, nullptr, out, gstat, gn2s, gn2b);
}

// Round 7
// 220.493 us; speedup vs baseline: 1.3111x; 1.0244x over previous
//
#include <hip/hip_runtime.h>
#include <cmath>

#define BB 4
#define CC 128
#define HH 64
#define WW 64
#define SP 4096   // H*W
#define NG 32     // groups
#define TT 64     // attention uv-tile width
#define NS 2      // attention uv split factor
#define PSZ ((size_t)BB * SP * CC)   // partial tensor elements

typedef __bf16 bf16x8 __attribute__((ext_vector_type(8)));
typedef __bf16 bf16x4 __attribute__((ext_vector_type(4)));
typedef float  f32x4  __attribute__((ext_vector_type(4)));

__device__ __forceinline__ float silu_f(float v) {
    return v / (1.f + __expf(-v));
}

__device__ __forceinline__ float fast_exp2(float x) {
    return exp2f(x);   // v_exp_f32
}

// DPP-based add of lane^mask partner within each row of 16 (VALU pipe, not LDS).
template<int CTRL>
__device__ __forceinline__ float dpp_add(float v) {
    int m = __builtin_amdgcn_update_dpp(0, __float_as_int(v), CTRL, 0xF, 0xF, true);
    return v + __int_as_float(m);
}
// 16-lane sum (over lane bits 0..3): xor1, xor2 (quad_perm), then after quads are
// uniform, row_half_mirror (= +quad^1) and row_mirror (= +quad^3) complete the sum.
__device__ __forceinline__ float row16_sum(float v) {
    v = dpp_add<0xB1>(v);    // quad_perm [1,0,3,2]  : + lane^1
    v = dpp_add<0x4E>(v);    // quad_perm [2,3,0,1]  : + lane^2
    v = dpp_add<0x141>(v);   // row_half_mirror      : + other quad in half
    v = dpp_add<0x140>(v);   // row_mirror           : + other half of row
    return v;
}

// ================= merged prep kernel (slim LDS) =================
__global__ __launch_bounds__(256) void prep_kernel(
    const float* __restrict__ x, const float* __restrict__ gn1s,
    const float* __restrict__ gn1b, __bf16* __restrict__ aT,
    const float* __restrict__ c1w, const float* __restrict__ c2w,
    __bf16* __restrict__ wt,
    const float* __restrict__ t, const float* __restrict__ mlpw,
    const float* __restrict__ mlpb, float* __restrict__ tembw,
    const float* __restrict__ cond, const float* __restrict__ cw,
    const float* __restrict__ cb, __bf16* __restrict__ cmT,
    __bf16* __restrict__ cm2)
{
    __shared__ __align__(16) char pool[18432];
    __shared__ float rs[4], rs2[4], mean_s, inv_s;
    const int blk = blockIdx.x;
    const int tid = threadIdx.x;

    if (blk < 128) {
        // ---- GN1 two-pass ----
        const int b = blk >> 5, g = blk & 31;
        const float* p = x + (size_t)blk * 16384;
        float s = 0.f, s2 = 0.f;
        for (int it = 0; it < 16; ++it) {
            int q = it * 256 + tid;
            float4 v = *(const float4*)&p[q * 4];
            s += v.x + v.y + v.z + v.w;
            s2 += v.x * v.x + v.y * v.y + v.z * v.z + v.w * v.w;
        }
        #pragma unroll
        for (int off = 32; off >= 1; off >>= 1) {
            s  += __shfl_down(s,  off, 64);
            s2 += __shfl_down(s2, off, 64);
        }
        const int wid = tid >> 6;
        if ((tid & 63) == 0) { rs[wid] = s; rs2[wid] = s2; }
        __syncthreads();
        if (tid == 0) {
            float S = rs[0] + rs[1] + rs[2] + rs[3];
            float S2 = rs2[0] + rs2[1] + rs2[2] + rs2[3];
            float m = S * (1.f / 16384.f);
            float var = S2 * (1.f / 16384.f) - m * m;
            mean_s = m;
            inv_s = rsqrtf(var + 1e-5f);
        }
        __syncthreads();
        const float m = mean_s, inv = inv_s;
        float sc[4], bi[4];
        #pragma unroll
        for (int j = 0; j < 4; ++j) { sc[j] = gn1s[g * 4 + j]; bi[j] = gn1b[g * 4 + j]; }
        for (int it = 0; it < 16; ++it) {
            int pp = it * 256 + tid;
            bf16x4 o;
            #pragma unroll
            for (int j = 0; j < 4; ++j)
                o[j] = (__bf16)silu_f((p[j * 4096 + pp] - m) * inv * sc[j] + bi[j]);
            *(bf16x4*)&aT[((size_t)(b * SP + pp)) * CC + g * 4] = o;
        }
    } else if (blk < 146) {
        // ---- weight transpose ----
        const int idx = blk - 128;
        const int wsel = idx / 9, tap = idx % 9;
        const float* src = wsel ? c2w : c1w;
        __bf16* dst = wt + (size_t)wsel * 9 * 16384 + (size_t)tap * 16384;
        for (int it = 0; it < 64; ++it) {
            int q = it * 256 + tid;
            dst[q] = (__bf16)src[(size_t)q * 9 + tap];
        }
    } else if (blk < 154) {
        // ---- temb MLP ----
        const int cog = blk - 146;
        float* st = (float*)pool;
        for (int it = 0; it < 8; ++it) {
            int q = it * 256 + tid;
            st[q] = silu_f(t[q]);
        }
        __syncthreads();
        const int col = tid >> 4, seg = tid & 15;
        const float* wr = mlpw + (size_t)(cog * 16 + col) * 512 + seg * 32;
        float acc[4] = {0.f, 0.f, 0.f, 0.f};
        #pragma unroll
        for (int k8 = 0; k8 < 8; ++k8) {
            float4 wv = *(const float4*)&wr[k8 * 4];
            #pragma unroll
            for (int j = 0; j < 4; ++j) {
                int k = seg * 32 + k8 * 4 + j;
                float w4 = (&wv.x)[j];
                acc[0] += st[0 * 512 + k] * w4;
                acc[1] += st[1 * 512 + k] * w4;
                acc[2] += st[2 * 512 + k] * w4;
                acc[3] += st[3 * 512 + k] * w4;
            }
        }
        #pragma unroll
        for (int o = 1; o < 16; o <<= 1) {
            #pragma unroll
            for (int b4 = 0; b4 < 4; ++b4)
                acc[b4] += __shfl_xor(acc[b4], o, 64);
        }
        if (seg == 0) {
            float bv = mlpb[cog * 16 + col];
            #pragma unroll
            for (int b4 = 0; b4 < 4; ++b4)
                tembw[b4 * 128 + cog * 16 + col] = acc[b4] + bv;
        }
    } else {
        // ---- 1x1 conv MFMA ----
        const int pblk = blk - 154;
        const int b = pblk >> 6;
        const int p0 = (pblk & 63) * 64;
        const int l = tid & 63, wv = tid >> 6;
        const int l15 = l & 15, l4 = l >> 4;
        const int mB = wv * 32;

        __bf16* XT = (__bf16*)pool;

        for (int it = 0; it < 32; ++it) {
            int q = it * 256 + tid;
            float v = cond[((size_t)(b * CC + (q >> 6))) * SP + p0 + (q & 63)];
            XT[(q & 63) * 136 + (q >> 6)] = (__bf16)v;
        }
        __syncthreads();

        f32x4 acc[2][4];
        #pragma unroll
        for (int mb = 0; mb < 2; ++mb)
            #pragma unroll
            for (int nt = 0; nt < 4; ++nt) acc[mb][nt] = (f32x4){0.f, 0.f, 0.f, 0.f};

        #pragma unroll
        for (int ks = 0; ks < 4; ++ks) {
            bf16x8 bfr[4];
            #pragma unroll
            for (int nt = 0; nt < 4; ++nt)
                bfr[nt] = *(const bf16x8*)&XT[(nt * 16 + l15) * 136 + ks * 32 + l4 * 8];
            #pragma unroll
            for (int mb = 0; mb < 2; ++mb) {
                const float* wrow = cw + (size_t)(mB + mb * 16 + l15) * 128 + ks * 32 + l4 * 8;
                float4 wa = *(const float4*)wrow;
                float4 wb4 = *(const float4*)(wrow + 4);
                bf16x8 afr;
                afr[0] = (__bf16)wa.x; afr[1] = (__bf16)wa.y;
                afr[2] = (__bf16)wa.z; afr[3] = (__bf16)wa.w;
                afr[4] = (__bf16)wb4.x; afr[5] = (__bf16)wb4.y;
                afr[6] = (__bf16)wb4.z; afr[7] = (__bf16)wb4.w;
                #pragma unroll
                for (int nt = 0; nt < 4; ++nt)
                    acc[mb][nt] = __builtin_amdgcn_mfma_f32_16x16x32_bf16(afr, bfr[nt], acc[mb][nt], 0, 0, 0);
            }
        }

        // scale = log2(e)/sqrt(128): folds the softmax temperature AND the
        // exp->exp2 conversion into the attention K operand (cmT is only ever
        // consumed as the QK^T A-operand in attn_kernel).
        const float scl = 0.12751743f;
        #pragma unroll
        for (int mb = 0; mb < 2; ++mb) {
            int co0 = mB + mb * 16 + l4 * 4;
            float bv[4];
            #pragma unroll
            for (int r = 0; r < 4; ++r) bv[r] = cb[co0 + r];
            #pragma unroll
            for (int nt = 0; nt < 4; ++nt) {
                int p = p0 + nt * 16 + l15;
                bf16x4 o;
                #pragma unroll
                for (int r = 0; r < 4; ++r)
                    o[r] = (__bf16)((acc[mb][nt][r] + bv[r]) * scl);
                *(bf16x4*)&cmT[((size_t)(b * SP + p)) * CC + co0] = o;
            }
        }
        __syncthreads();
        __bf16* O2 = (__bf16*)pool;
        #pragma unroll
        for (int mb = 0; mb < 2; ++mb) {
            int co0 = mB + mb * 16 + l4 * 4;
            #pragma unroll
            for (int r = 0; r < 4; ++r) {
                float bv = cb[co0 + r];
                #pragma unroll
                for (int nt = 0; nt < 4; ++nt)
                    O2[(co0 + r) * 72 + nt * 16 + l15] = (__bf16)(acc[mb][nt][r] + bv);
            }
        }
        __syncthreads();
        #pragma unroll
        for (int it = 0; it < 4; ++it) {
            int q = it * 256 + tid;
            int co = q >> 3, pc = q & 7;
            *(bf16x8*)&cm2[((size_t)(b * CC + co)) * SP + p0 + pc * 8] =
                *(const bf16x8*)&O2[co * 72 + pc * 8];
        }
    }
}

// ---------------- 3x3 conv: optional fused GN+SiLU on staging ----------------
template<bool FUSE_TEMB, bool OUT_CF, bool FUSE_GN>
__global__ __launch_bounds__(256, 4) void conv_mfma_kernel(
    const __bf16* __restrict__ inT, const __bf16* __restrict__ wt,
    const float* __restrict__ bias, const float* __restrict__ temb,
    const float* __restrict__ resid, __bf16* __restrict__ outT,
    float* __restrict__ outF, const float* __restrict__ gstat,
    const float* __restrict__ gn_s, const float* __restrict__ gn_b)
{
    const int y   = blockIdx.x >> 2;
    const int xh2 = (blockIdx.x >> 1) & 1;
    const int coh = blockIdx.x & 1;
    const int x0  = xh2 * 32;
    const int b   = blockIdx.y;
    const int tid = threadIdx.x;
    const int l = tid & 63, wv = tid >> 6;
    const int l15 = l & 15, l4 = l >> 4;
    const int co_w = coh * 64 + wv * 16;

    __shared__ __bf16 inS[3 * 16 * 34 * 8];   // 26 KB
    __shared__ float af[128], bfp[128];

    if (FUSE_GN) {
        if (tid < 128) {
            int g = tid >> 2;
            float S = gstat[(b * NG + g) * 2], S2 = gstat[(b * NG + g) * 2 + 1];
            float m = S * (1.f / 16384.f);
            float var = S2 * (1.f / 16384.f) - m * m;
            float inv = rsqrtf(var + 1e-5f);
            float a = inv * gn_s[tid];
            af[tid] = a;
            bfp[tid] = gn_b[tid] - m * a;
        }
        __syncthreads();
    }

    const __bf16* inTb = inT + (size_t)b * SP * CC;
    for (int q = tid; q < 3 * 34 * 16; q += 256) {
        int cc = q & 15;
        int t2 = q >> 4;
        int xs = t2 % 34;
        int r  = t2 / 34;
        int yy = y + r - 1;
        int xg = x0 + xs - 1;
        bf16x8 v;
        if (((unsigned)yy < 64u) && ((unsigned)xg < 64u)) {
            bf16x8 raw = *(const bf16x8*)&inTb[((size_t)(yy * 64 + xg)) * CC + cc * 8];
            if (FUSE_GN) {
                #pragma unroll
                for (int j = 0; j < 8; ++j) {
                    int c = cc * 8 + j;
                    v[j] = (__bf16)silu_f((float)raw[j] * af[c] + bfp[c]);
                }
            } else {
                v = raw;
            }
        } else {
            #pragma unroll
            for (int j = 0; j < 8; ++j) v[j] = (__bf16)0.f;
        }
        *(bf16x8*)&inS[((r * 16 + cc) * 34 + xs) * 8] = v;
    }
    __syncthreads();

    f32x4 acc[2];
    acc[0] = (f32x4){0.f, 0.f, 0.f, 0.f};
    acc[1] = (f32x4){0.f, 0.f, 0.f, 0.f};

    const __bf16* wp = wt + (size_t)(co_w + l15) * 128 + l4 * 8;
    bf16x8 wb[2][4];
    #pragma unroll
    for (int ks = 0; ks < 4; ++ks)
        wb[0][ks] = *(const bf16x8*)(wp + ks * 32);

    #pragma unroll
    for (int tap = 0; tap < 9; ++tap) {
        const int cur = tap & 1, nxt = cur ^ 1;
        if (tap < 8) {
            #pragma unroll
            for (int ks = 0; ks < 4; ++ks)
                wb[nxt][ks] = *(const bf16x8*)(wp + (tap + 1) * 16384 + ks * 32);
        }
        const int rr = tap / 3, dx = tap % 3;
        #pragma unroll
        for (int ks = 0; ks < 4; ++ks) {
            const __bf16* rb = &inS[((rr * 16 + ks * 4 + l4) * 34) * 8];
            bf16x8 b0 = *(const bf16x8*)&rb[(dx + l15) * 8];
            bf16x8 b1 = *(const bf16x8*)&rb[(16 + dx + l15) * 8];
            acc[0] = __builtin_amdgcn_mfma_f32_16x16x32_bf16(wb[cur][ks], b0, acc[0], 0, 0, 0);
            acc[1] = __builtin_amdgcn_mfma_f32_16x16x32_bf16(wb[cur][ks], b1, acc[1], 0, 0, 0);
        }
    }

    if (OUT_CF) {
        #pragma unroll
        for (int r = 0; r < 4; ++r) {
            int co = co_w + l4 * 4 + r;
            float bv = bias[co];
            #pragma unroll
            for (int nb = 0; nb < 2; ++nb) {
                int p = y * 64 + x0 + nb * 16 + l15;
                size_t o = ((size_t)(b * CC + co)) * SP + p;
                outF[o] = acc[nb][r] + bv + resid[o];
            }
        }
    } else {
        int co0 = co_w + l4 * 4;
        float bv[4];
        #pragma unroll
        for (int r = 0; r < 4; ++r)
            bv[r] = bias[co0 + r] + (FUSE_TEMB ? temb[b * CC + co0 + r] : 0.f);
        #pragma unroll
        for (int nb = 0; nb < 2; ++nb) {
            int p = y * 64 + x0 + nb * 16 + l15;
            bf16x4 o;
            #pragma unroll
            for (int r = 0; r < 4; ++r)
                o[r] = (__bf16)(acc[nb][r] + bv[r]);
            *(bf16x4*)&outT[((size_t)(b * SP + p)) * CC + co0] = o;
        }
    }
}

// ---------------- fused cross-attention v12: producer/consumer waves ----------------
// Lesson ladder: one wave cannot hold Q(64 regs)+acc(32)+transients under any
// budget allowing >2 waves/SIMD (256-budget: 2 waves; 168: spills; 128:
// catastrophic). And Q-in-LDS (v11) re-reads 16KB/wave-iter -> LDS-pipe bound.
// v12: 512-thread blocks. Waves 0-3 = producers (QK^T+softmax, hold Q in regs,
// no acc); waves 4-7 = consumers (PV, hold acc, no Q). Separate loops with
// identical barrier counts -> hfr/acc2 live ranges are disjoint -> ~120 regs
// fits launch_bounds(512,4)'s 128 budget -> 4 waves/SIMD = 2 blocks/CU = 50%.
// Pb and ct2 both double-buffered; ONE barrier per iteration. NS=2: grid 512
// blocks = exactly 2/CU.
#define CT2 72    // ct2 row stride (bf16)
#define PBS 72    // Pb row stride (bf16)
// pool: ct2[2] 2x18432 B, Pb[2] 2x9216 B -> 55296 B
#define POOL_BYTES 55296
#define NIT (SP / TT / NS)   // 32

__global__ __launch_bounds__(512, 4) void attn_kernel(
    const __bf16* __restrict__ h1T, const __bf16* __restrict__ cmT,
    const __bf16* __restrict__ cm2, __bf16* __restrict__ parts)
{
    const int w = blockIdx.x;
    const int b = blockIdx.y;
    const int s = blockIdx.z;
    const int tid = threadIdx.x;
    const int wid = tid >> 6;
    const int l = tid & 63, l15 = l & 15, l4 = l >> 4;

    __shared__ __align__(16) char pool[POOL_BYTES];
    __bf16* ct2p = (__bf16*)pool;               // 2 buffers of 9216 elems
    __bf16* Pbp  = (__bf16*)(pool + 36864);     // 2 buffers of 4608 elems
    __bf16* Otr  = (__bf16*)pool;               // epilogue alias

    const __bf16* h1Tb = h1T + (size_t)b * SP * CC;
    const __bf16* cmTb = cmT + (size_t)b * SP * CC;
    const __bf16* cm2b = cm2 + (size_t)b * CC * SP;

    if (wid < 4) {
        // ================= producer: QK^T + softmax =================
        const int pw = wid;   // owns 16 uv rows of each tile
        bf16x8 hfr[4][4];     // Q: 64h x 128c, register-resident
        #pragma unroll
        for (int nt = 0; nt < 4; ++nt)
            #pragma unroll
            for (int ks = 0; ks < 4; ++ks)
                hfr[nt][ks] = *(const bf16x8*)&h1Tb[((size_t)((nt * 16 + l15) * WW + w)) * CC + ks * 32 + l4 * 8];

        // P[0] -> Pb[0]
        {
            const int uv0 = s * TT;
            const __bf16* arow = cmTb + (size_t)(uv0 + 16 * pw + l15) * CC;
            bf16x8 afr[4];
            #pragma unroll
            for (int ks = 0; ks < 4; ++ks) afr[ks] = *(const bf16x8*)&arow[ks * 32 + l4 * 8];
            f32x4 s1[4];
            __builtin_amdgcn_s_setprio(1);
            #pragma unroll
            for (int nt = 0; nt < 4; ++nt) {
                s1[nt] = (f32x4){0.f, 0.f, 0.f, 0.f};
                #pragma unroll
                for (int ks = 0; ks < 4; ++ks)
                    s1[nt] = __builtin_amdgcn_mfma_f32_16x16x32_bf16(afr[ks], hfr[nt][ks], s1[nt], 0, 0, 0);
            }
            __builtin_amdgcn_s_setprio(0);
            #pragma unroll
            for (int r = 0; r < 4; ++r) {
                float e0 = fast_exp2(s1[0][r]), e1 = fast_exp2(s1[1][r]);
                float e2 = fast_exp2(s1[2][r]), e3 = fast_exp2(s1[3][r]);
                float sm = (e0 + e1) + (e2 + e3);
                sm = row16_sum(sm);
                float ri = 1.f / sm;
                s1[0][r] = e0 * ri; s1[1][r] = e1 * ri;
                s1[2][r] = e2 * ri; s1[3][r] = e3 * ri;
            }
            #pragma unroll
            for (int nt = 0; nt < 4; ++nt) {
                bf16x4 pk;
                pk[0] = (__bf16)s1[nt][0]; pk[1] = (__bf16)s1[nt][1];
                pk[2] = (__bf16)s1[nt][2]; pk[3] = (__bf16)s1[nt][3];
                *(bf16x4*)&Pbp[(nt * 16 + l15) * PBS + 16 * pw + l4 * 4] = pk;
            }
        }
        __syncthreads();   // #1: Pb[0] + ct2[0] ready

        for (int i = 0; i < NIT; ++i) {
            if (i < NIT - 1) {
                const int uv0n = ((i + 1) * NS + s) * TT;
                const __bf16* arow = cmTb + (size_t)(uv0n + 16 * pw + l15) * CC;
                bf16x8 afr[4];
                #pragma unroll
                for (int ks = 0; ks < 4; ++ks) afr[ks] = *(const bf16x8*)&arow[ks * 32 + l4 * 8];
                f32x4 s1[4];
                __builtin_amdgcn_s_setprio(1);
                #pragma unroll
                for (int nt = 0; nt < 4; ++nt) {
                    s1[nt] = (f32x4){0.f, 0.f, 0.f, 0.f};
                    #pragma unroll
                    for (int ks = 0; ks < 4; ++ks)
                        s1[nt] = __builtin_amdgcn_mfma_f32_16x16x32_bf16(afr[ks], hfr[nt][ks], s1[nt], 0, 0, 0);
                }
                __builtin_amdgcn_s_setprio(0);
                #pragma unroll
                for (int r = 0; r < 4; ++r) {
                    float e0 = fast_exp2(s1[0][r]), e1 = fast_exp2(s1[1][r]);
                    float e2 = fast_exp2(s1[2][r]), e3 = fast_exp2(s1[3][r]);
                    float sm = (e0 + e1) + (e2 + e3);
                    sm = row16_sum(sm);
                    float ri = 1.f / sm;
                    s1[0][r] = e0 * ri; s1[1][r] = e1 * ri;
                    s1[2][r] = e2 * ri; s1[3][r] = e3 * ri;
                }
                __bf16* PbW = Pbp + ((i & 1) ^ 1) * 4608;
                #pragma unroll
                for (int nt = 0; nt < 4; ++nt) {
                    bf16x4 pk;
                    pk[0] = (__bf16)s1[nt][0]; pk[1] = (__bf16)s1[nt][1];
                    pk[2] = (__bf16)s1[nt][2]; pk[3] = (__bf16)s1[nt][3];
                    *(bf16x4*)&PbW[(nt * 16 + l15) * PBS + 16 * pw + l4 * 4] = pk;
                }
            }
            __syncthreads();   // per-iter barrier (matches consumer)
        }
    } else {
        // ================= consumer: PV accumulate =================
        const int cw = wid - 4;
        const int hB = (cw & 1) * 32;
        const int cB = (cw >> 1) * 64;
        const int tc = tid - 256;       // 0..255 within consumer group
        const int sc = tc >> 3;
        const int stc = tc & 7;

        f32x4 acc2[2][4];
        #pragma unroll
        for (int mb = 0; mb < 2; ++mb)
            #pragma unroll
            for (int nt = 0; nt < 4; ++nt) acc2[mb][nt] = (f32x4){0.f, 0.f, 0.f, 0.f};

        // stage ct2[0]
        {
            const int uv0 = s * TT;
            #pragma unroll
            for (int it = 0; it < 4; ++it) {
                int c = it * 32 + sc;
                *(bf16x8*)&ct2p[c * CT2 + stc * 8] =
                    *(const bf16x8*)&cm2b[(size_t)c * SP + uv0 + stc * 8];
            }
        }
        __syncthreads();   // #1: Pb[0] + ct2[0] ready

        for (int i = 0; i < NIT; ++i) {
            const int cur = i & 1;
            // prefetch ct2 tile i+1 into registers
            bf16x8 st4[4];
            if (i < NIT - 1) {
                const int uv0n = ((i + 1) * NS + s) * TT;
                #pragma unroll
                for (int it = 0; it < 4; ++it) {
                    int c = it * 32 + sc;
                    st4[it] = *(const bf16x8*)&cm2b[(size_t)c * SP + uv0n + stc * 8];
                }
            }
            // consume tile i
            {
                const __bf16* PbR = Pbp + cur * 4608;
                const __bf16* ctR = ct2p + cur * 9216;
                bf16x8 pfr[2][2];
                #pragma unroll
                for (int mb = 0; mb < 2; ++mb)
                    #pragma unroll
                    for (int ks = 0; ks < 2; ++ks)
                        pfr[mb][ks] = *(const bf16x8*)&PbR[(hB + mb * 16 + l15) * PBS + ks * 32 + l4 * 8];
                bf16x8 bfr[4][2];
                #pragma unroll
                for (int nt = 0; nt < 4; ++nt)
                    #pragma unroll
                    for (int ks = 0; ks < 2; ++ks)
                        bfr[nt][ks] = *(const bf16x8*)&ctR[(cB + nt * 16 + l15) * CT2 + ks * 32 + l4 * 8];
                __builtin_amdgcn_s_setprio(1);
                #pragma unroll
                for (int mb = 0; mb < 2; ++mb)
                    #pragma unroll
                    for (int nt = 0; nt < 4; ++nt)
                        #pragma unroll
                        for (int ks = 0; ks < 2; ++ks)
                            acc2[mb][nt] = __builtin_amdgcn_mfma_f32_16x16x32_bf16(
                                pfr[mb][ks], bfr[nt][ks], acc2[mb][nt], 0, 0, 0);
                __builtin_amdgcn_s_setprio(0);
            }
            // write ct2 tile i+1 into the other buffer
            if (i < NIT - 1) {
                __bf16* ctW = ct2p + (cur ^ 1) * 9216;
                #pragma unroll
                for (int it = 0; it < 4; ++it) {
                    int c = it * 32 + sc;
                    *(bf16x8*)&ctW[c * CT2 + stc * 8] = st4[it];
                }
            }
            __syncthreads();   // per-iter barrier (matches producer)
        }

        // consumers hold the output: transpose-stage into LDS
        #pragma unroll
        for (int mb = 0; mb < 2; ++mb)
            #pragma unroll
            for (int nt = 0; nt < 4; ++nt)
                #pragma unroll
                for (int r = 0; r < 4; ++r)
                    Otr[(hB + mb * 16 + l4 * 4 + r) * 136 + cB + nt * 16 + l15] =
                        (__bf16)acc2[mb][nt][r];
    }

    __syncthreads();   // convergent: Otr complete
    __bf16* pO = parts + (size_t)s * PSZ;
    #pragma unroll
    for (int it = 0; it < 2; ++it) {
        int q = it * 512 + tid;
        int h = q >> 4, cc = q & 15;
        *(bf16x8*)&pO[((size_t)(b * SP + h * WW + w)) * CC + cc * 8] =
            *(const bf16x8*)&Otr[h * 136 + cc * 8];
    }
}

// ---------------- GN2 stats: h2 -> h2T bf16 + atomic group sums ----------------
__global__ __launch_bounds__(256) void gn2_stats_kernel(
    const __bf16* __restrict__ h1T, const __bf16* __restrict__ parts,
    const int* __restrict__ aim, const float* __restrict__ emb,
    __bf16* __restrict__ h2T, float* __restrict__ gstat)
{
    const int pb = blockIdx.x, b = blockIdx.y;
    const int tid = threadIdx.x;
    const int c4 = tid & 31;
    const float4 ev = *(const float4*)&emb[aim[b] * CC + c4 * 4];
    float s = 0.f, s2 = 0.f;
    for (int it = 0; it < 8; ++it) {
        int prow = it * 8 + (tid >> 5);
        size_t base = ((size_t)(b * SP + pb * 64 + prow)) * CC + c4 * 4;
        bf16x4 hv = *(const bf16x4*)&h1T[base];
        float v0 = (float)hv[0] + ev.x;
        float v1 = (float)hv[1] + ev.y;
        float v2 = (float)hv[2] + ev.z;
        float v3 = (float)hv[3] + ev.w;
        #pragma unroll
        for (int k = 0; k < NS; ++k) {
            bf16x4 a = *(const bf16x4*)&parts[(size_t)k * PSZ + base];
            v0 += (float)a[0]; v1 += (float)a[1];
            v2 += (float)a[2]; v3 += (float)a[3];
        }
        bf16x4 o;
        o[0] = (__bf16)v0; o[1] = (__bf16)v1;
        o[2] = (__bf16)v2; o[3] = (__bf16)v3;
        *(bf16x4*)&h2T[base] = o;
        s += v0 + v1 + v2 + v3;
        s2 += v0 * v0 + v1 * v1 + v2 * v2 + v3 * v3;
    }
    s  += __shfl_down(s,  32, 64);
    s2 += __shfl_down(s2, 32, 64);
    __shared__ float ls[4][32][2];
    const int wv = tid >> 6, ll = tid & 63;
    if (ll < 32) { ls[wv][ll][0] = s; ls[wv][ll][1] = s2; }
    __syncthreads();
    if (tid < 32) {
        float S = ls[0][tid][0] + ls[1][tid][0] + ls[2][tid][0] + ls[3][tid][0];
        float S2 = ls[0][tid][1] + ls[1][tid][1] + ls[2][tid][1] + ls[3][tid][1];
        atomicAdd(&gstat[(b * NG + tid) * 2], S);
        atomicAdd(&gstat[(b * NG + tid) * 2 + 1], S2);
    }
}

extern "C" void kernel_launch(void* const* d_in, const int* in_sizes, int n_in,
                              void* d_out, int out_size, void* d_ws, size_t ws_size,
                              hipStream_t stream)
{
    const float* x     = (const float*)d_in[0];
    const float* t     = (const float*)d_in[1];
    const int*   aim   = (const int*)  d_in[2];
    const float* cond  = (const float*)d_in[3];
    const float* gn1s  = (const float*)d_in[4];
    const float* gn1b  = (const float*)d_in[5];
    const float* c1w   = (const float*)d_in[6];
    const float* c1b   = (const float*)d_in[7];
    const float* mlpw  = (const float*)d_in[8];
    const float* mlpb  = (const float*)d_in[9];
    const float* cw    = (const float*)d_in[10];
    const float* cb    = (const float*)d_in[11];
    const float* gn2s  = (const float*)d_in[12];
    const float* gn2b  = (const float*)d_in[13];
    const float* c2w   = (const float*)d_in[14];
    const float* c2b   = (const float*)d_in[15];
    const float* emb   = (const float*)d_in[16];
    float* out = (float*)d_out;
    float* ws = (float*)d_ws;

    // float-offset workspace map
    __bf16* aT    = (__bf16*)ws;                  // [0, 1048576)
    __bf16* h1T   = (__bf16*)(ws + 1048576);
    __bf16* cmT   = (__bf16*)(ws + 2097152);      // h2T after attn
    __bf16* cm2   = (__bf16*)(ws + 3145728);
    __bf16* parts = (__bf16*)(ws + 4194304);      // 2 partials
    __bf16* wt    = (__bf16*)(ws + 6291456);
    float*  tembw = ws + 6438912;
    float*  gstat = ws + 6439424;                 // 256 floats
    __bf16* h2T   = cmT;

    prep_kernel<<<dim3(410), dim3(256), 0, stream>>>(
        x, gn1s, gn1b, aT, c1w, c2w, wt, t, mlpw, mlpb, tembw,
        cond, cw, cb, cmT, cm2);
    hipMemsetAsync(gstat, 0, 256 * sizeof(float), stream);
    conv_mfma_kernel<true, false, false><<<dim3(256, BB), dim3(256), 0, stream>>>(
        aT, wt, c1b, tembw, nullptr, h1T, nullptr, nullptr, nullptr, nullptr);
    attn_kernel<<<dim3(WW, BB, NS), dim3(512), 0, stream>>>(h1T, cmT, cm2, parts);
    gn2_stats_kernel<<<dim3(64, BB), dim3(256), 0, stream>>>(h1T, parts, aim, emb, h2T, gstat);
    conv_mfma_kernel<false, true, true><<<dim3(256, BB), dim3(256), 0, stream>>>(
        h2T, wt + (size_t)9 * 16384, c2b, nullptr, x, nullptr, out, gstat, gn2s, gn2b);
}

// Round 8
// 210.811 us; speedup vs baseline: 1.3713x; 1.0459x over previous
//
#include <hip/hip_runtime.h>
#include <cmath>

#define BB 4
#define CC 128
#define HH 64
#define WW 64
#define SP 4096   // H*W
#define NG 32     // groups
#define TT 64     // attention uv-tile width
#define NS 2      // attention uv split factor
#define PSZ ((size_t)BB * SP * CC)   // partial tensor elements

typedef __bf16 bf16x8 __attribute__((ext_vector_type(8)));
typedef __bf16 bf16x4 __attribute__((ext_vector_type(4)));
typedef float  f32x4  __attribute__((ext_vector_type(4)));

__device__ __forceinline__ float silu_f(float v) {
    return v / (1.f + __expf(-v));
}

__device__ __forceinline__ float fast_exp2(float x) {
    return exp2f(x);   // v_exp_f32
}

// DPP-based add of lane^mask partner within each row of 16 (VALU pipe, not LDS).
template<int CTRL>
__device__ __forceinline__ float dpp_add(float v) {
    int m = __builtin_amdgcn_update_dpp(0, __float_as_int(v), CTRL, 0xF, 0xF, true);
    return v + __int_as_float(m);
}
// 16-lane sum (over lane bits 0..3): xor1, xor2 (quad_perm), then after quads are
// uniform, row_half_mirror (= +quad^1) and row_mirror (= +quad^3) complete the sum.
__device__ __forceinline__ float row16_sum(float v) {
    v = dpp_add<0xB1>(v);    // quad_perm [1,0,3,2]  : + lane^1
    v = dpp_add<0x4E>(v);    // quad_perm [2,3,0,1]  : + lane^2
    v = dpp_add<0x141>(v);   // row_half_mirror      : + other quad in half
    v = dpp_add<0x140>(v);   // row_mirror           : + other half of row
    return v;
}

// ================= merged prep kernel (slim LDS) =================
__global__ __launch_bounds__(256) void prep_kernel(
    const float* __restrict__ x, const float* __restrict__ gn1s,
    const float* __restrict__ gn1b, __bf16* __restrict__ aT,
    const float* __restrict__ c1w, const float* __restrict__ c2w,
    __bf16* __restrict__ wt,
    const float* __restrict__ t, const float* __restrict__ mlpw,
    const float* __restrict__ mlpb, float* __restrict__ tembw,
    const float* __restrict__ cond, const float* __restrict__ cw,
    const float* __restrict__ cb, __bf16* __restrict__ cmT,
    __bf16* __restrict__ cm2)
{
    __shared__ __align__(16) char pool[18432];
    __shared__ float rs[4], rs2[4], mean_s, inv_s;
    const int blk = blockIdx.x;
    const int tid = threadIdx.x;

    if (blk < 128) {
        // ---- GN1 two-pass ----
        const int b = blk >> 5, g = blk & 31;
        const float* p = x + (size_t)blk * 16384;
        float s = 0.f, s2 = 0.f;
        for (int it = 0; it < 16; ++it) {
            int q = it * 256 + tid;
            float4 v = *(const float4*)&p[q * 4];
            s += v.x + v.y + v.z + v.w;
            s2 += v.x * v.x + v.y * v.y + v.z * v.z + v.w * v.w;
        }
        #pragma unroll
        for (int off = 32; off >= 1; off >>= 1) {
            s  += __shfl_down(s,  off, 64);
            s2 += __shfl_down(s2, off, 64);
        }
        const int wid = tid >> 6;
        if ((tid & 63) == 0) { rs[wid] = s; rs2[wid] = s2; }
        __syncthreads();
        if (tid == 0) {
            float S = rs[0] + rs[1] + rs[2] + rs[3];
            float S2 = rs2[0] + rs2[1] + rs2[2] + rs2[3];
            float m = S * (1.f / 16384.f);
            float var = S2 * (1.f / 16384.f) - m * m;
            mean_s = m;
            inv_s = rsqrtf(var + 1e-5f);
        }
        __syncthreads();
        const float m = mean_s, inv = inv_s;
        float sc[4], bi[4];
        #pragma unroll
        for (int j = 0; j < 4; ++j) { sc[j] = gn1s[g * 4 + j]; bi[j] = gn1b[g * 4 + j]; }
        for (int it = 0; it < 16; ++it) {
            int pp = it * 256 + tid;
            bf16x4 o;
            #pragma unroll
            for (int j = 0; j < 4; ++j)
                o[j] = (__bf16)silu_f((p[j * 4096 + pp] - m) * inv * sc[j] + bi[j]);
            *(bf16x4*)&aT[((size_t)(b * SP + pp)) * CC + g * 4] = o;
        }
    } else if (blk < 146) {
        // ---- weight transpose ----
        const int idx = blk - 128;
        const int wsel = idx / 9, tap = idx % 9;
        const float* src = wsel ? c2w : c1w;
        __bf16* dst = wt + (size_t)wsel * 9 * 16384 + (size_t)tap * 16384;
        for (int it = 0; it < 64; ++it) {
            int q = it * 256 + tid;
            dst[q] = (__bf16)src[(size_t)q * 9 + tap];
        }
    } else if (blk < 154) {
        // ---- temb MLP ----
        const int cog = blk - 146;
        float* st = (float*)pool;
        for (int it = 0; it < 8; ++it) {
            int q = it * 256 + tid;
            st[q] = silu_f(t[q]);
        }
        __syncthreads();
        const int col = tid >> 4, seg = tid & 15;
        const float* wr = mlpw + (size_t)(cog * 16 + col) * 512 + seg * 32;
        float acc[4] = {0.f, 0.f, 0.f, 0.f};
        #pragma unroll
        for (int k8 = 0; k8 < 8; ++k8) {
            float4 wv = *(const float4*)&wr[k8 * 4];
            #pragma unroll
            for (int j = 0; j < 4; ++j) {
                int k = seg * 32 + k8 * 4 + j;
                float w4 = (&wv.x)[j];
                acc[0] += st[0 * 512 + k] * w4;
                acc[1] += st[1 * 512 + k] * w4;
                acc[2] += st[2 * 512 + k] * w4;
                acc[3] += st[3 * 512 + k] * w4;
            }
        }
        #pragma unroll
        for (int o = 1; o < 16; o <<= 1) {
            #pragma unroll
            for (int b4 = 0; b4 < 4; ++b4)
                acc[b4] += __shfl_xor(acc[b4], o, 64);
        }
        if (seg == 0) {
            float bv = mlpb[cog * 16 + col];
            #pragma unroll
            for (int b4 = 0; b4 < 4; ++b4)
                tembw[b4 * 128 + cog * 16 + col] = acc[b4] + bv;
        }
    } else {
        // ---- 1x1 conv MFMA ----
        const int pblk = blk - 154;
        const int b = pblk >> 6;
        const int p0 = (pblk & 63) * 64;
        const int l = tid & 63, wv = tid >> 6;
        const int l15 = l & 15, l4 = l >> 4;
        const int mB = wv * 32;

        __bf16* XT = (__bf16*)pool;

        for (int it = 0; it < 32; ++it) {
            int q = it * 256 + tid;
            float v = cond[((size_t)(b * CC + (q >> 6))) * SP + p0 + (q & 63)];
            XT[(q & 63) * 136 + (q >> 6)] = (__bf16)v;
        }
        __syncthreads();

        f32x4 acc[2][4];
        #pragma unroll
        for (int mb = 0; mb < 2; ++mb)
            #pragma unroll
            for (int nt = 0; nt < 4; ++nt) acc[mb][nt] = (f32x4){0.f, 0.f, 0.f, 0.f};

        #pragma unroll
        for (int ks = 0; ks < 4; ++ks) {
            bf16x8 bfr[4];
            #pragma unroll
            for (int nt = 0; nt < 4; ++nt)
                bfr[nt] = *(const bf16x8*)&XT[(nt * 16 + l15) * 136 + ks * 32 + l4 * 8];
            #pragma unroll
            for (int mb = 0; mb < 2; ++mb) {
                const float* wrow = cw + (size_t)(mB + mb * 16 + l15) * 128 + ks * 32 + l4 * 8;
                float4 wa = *(const float4*)wrow;
                float4 wb4 = *(const float4*)(wrow + 4);
                bf16x8 afr;
                afr[0] = (__bf16)wa.x; afr[1] = (__bf16)wa.y;
                afr[2] = (__bf16)wa.z; afr[3] = (__bf16)wa.w;
                afr[4] = (__bf16)wb4.x; afr[5] = (__bf16)wb4.y;
                afr[6] = (__bf16)wb4.z; afr[7] = (__bf16)wb4.w;
                #pragma unroll
                for (int nt = 0; nt < 4; ++nt)
                    acc[mb][nt] = __builtin_amdgcn_mfma_f32_16x16x32_bf16(afr, bfr[nt], acc[mb][nt], 0, 0, 0);
            }
        }

        // scale = log2(e)/sqrt(128): folds the softmax temperature AND the
        // exp->exp2 conversion into the attention K operand (cmT is only ever
        // consumed as the QK^T A-operand in attn_kernel).
        const float scl = 0.12751743f;
        #pragma unroll
        for (int mb = 0; mb < 2; ++mb) {
            int co0 = mB + mb * 16 + l4 * 4;
            float bv[4];
            #pragma unroll
            for (int r = 0; r < 4; ++r) bv[r] = cb[co0 + r];
            #pragma unroll
            for (int nt = 0; nt < 4; ++nt) {
                int p = p0 + nt * 16 + l15;
                bf16x4 o;
                #pragma unroll
                for (int r = 0; r < 4; ++r)
                    o[r] = (__bf16)((acc[mb][nt][r] + bv[r]) * scl);
                *(bf16x4*)&cmT[((size_t)(b * SP + p)) * CC + co0] = o;
            }
        }
        __syncthreads();
        __bf16* O2 = (__bf16*)pool;
        #pragma unroll
        for (int mb = 0; mb < 2; ++mb) {
            int co0 = mB + mb * 16 + l4 * 4;
            #pragma unroll
            for (int r = 0; r < 4; ++r) {
                float bv = cb[co0 + r];
                #pragma unroll
                for (int nt = 0; nt < 4; ++nt)
                    O2[(co0 + r) * 72 + nt * 16 + l15] = (__bf16)(acc[mb][nt][r] + bv);
            }
        }
        __syncthreads();
        #pragma unroll
        for (int it = 0; it < 4; ++it) {
            int q = it * 256 + tid;
            int co = q >> 3, pc = q & 7;
            *(bf16x8*)&cm2[((size_t)(b * CC + co)) * SP + p0 + pc * 8] =
                *(const bf16x8*)&O2[co * 72 + pc * 8];
        }
    }
}

// ---------------- 3x3 conv: optional fused GN+SiLU on staging ----------------
template<bool FUSE_TEMB, bool OUT_CF, bool FUSE_GN>
__global__ __launch_bounds__(256, 4) void conv_mfma_kernel(
    const __bf16* __restrict__ inT, const __bf16* __restrict__ wt,
    const float* __restrict__ bias, const float* __restrict__ temb,
    const float* __restrict__ resid, __bf16* __restrict__ outT,
    float* __restrict__ outF, const float* __restrict__ gstat,
    const float* __restrict__ gn_s, const float* __restrict__ gn_b)
{
    const int y   = blockIdx.x >> 2;
    const int xh2 = (blockIdx.x >> 1) & 1;
    const int coh = blockIdx.x & 1;
    const int x0  = xh2 * 32;
    const int b   = blockIdx.y;
    const int tid = threadIdx.x;
    const int l = tid & 63, wv = tid >> 6;
    const int l15 = l & 15, l4 = l >> 4;
    const int co_w = coh * 64 + wv * 16;

    __shared__ __bf16 inS[3 * 16 * 34 * 8];   // 26 KB
    __shared__ float af[128], bfp[128];

    if (FUSE_GN) {
        if (tid < 128) {
            int g = tid >> 2;
            float S = gstat[(b * NG + g) * 2], S2 = gstat[(b * NG + g) * 2 + 1];
            float m = S * (1.f / 16384.f);
            float var = S2 * (1.f / 16384.f) - m * m;
            float inv = rsqrtf(var + 1e-5f);
            float a = inv * gn_s[tid];
            af[tid] = a;
            bfp[tid] = gn_b[tid] - m * a;
        }
        __syncthreads();
    }

    const __bf16* inTb = inT + (size_t)b * SP * CC;
    for (int q = tid; q < 3 * 34 * 16; q += 256) {
        int cc = q & 15;
        int t2 = q >> 4;
        int xs = t2 % 34;
        int r  = t2 / 34;
        int yy = y + r - 1;
        int xg = x0 + xs - 1;
        bf16x8 v;
        if (((unsigned)yy < 64u) && ((unsigned)xg < 64u)) {
            bf16x8 raw = *(const bf16x8*)&inTb[((size_t)(yy * 64 + xg)) * CC + cc * 8];
            if (FUSE_GN) {
                #pragma unroll
                for (int j = 0; j < 8; ++j) {
                    int c = cc * 8 + j;
                    v[j] = (__bf16)silu_f((float)raw[j] * af[c] + bfp[c]);
                }
            } else {
                v = raw;
            }
        } else {
            #pragma unroll
            for (int j = 0; j < 8; ++j) v[j] = (__bf16)0.f;
        }
        *(bf16x8*)&inS[((r * 16 + cc) * 34 + xs) * 8] = v;
    }
    __syncthreads();

    f32x4 acc[2];
    acc[0] = (f32x4){0.f, 0.f, 0.f, 0.f};
    acc[1] = (f32x4){0.f, 0.f, 0.f, 0.f};

    const __bf16* wp = wt + (size_t)(co_w + l15) * 128 + l4 * 8;
    bf16x8 wb[2][4];
    #pragma unroll
    for (int ks = 0; ks < 4; ++ks)
        wb[0][ks] = *(const bf16x8*)(wp + ks * 32);

    #pragma unroll
    for (int tap = 0; tap < 9; ++tap) {
        const int cur = tap & 1, nxt = cur ^ 1;
        if (tap < 8) {
            #pragma unroll
            for (int ks = 0; ks < 4; ++ks)
                wb[nxt][ks] = *(const bf16x8*)(wp + (tap + 1) * 16384 + ks * 32);
        }
        const int rr = tap / 3, dx = tap % 3;
        #pragma unroll
        for (int ks = 0; ks < 4; ++ks) {
            const __bf16* rb = &inS[((rr * 16 + ks * 4 + l4) * 34) * 8];
            bf16x8 b0 = *(const bf16x8*)&rb[(dx + l15) * 8];
            bf16x8 b1 = *(const bf16x8*)&rb[(16 + dx + l15) * 8];
            acc[0] = __builtin_amdgcn_mfma_f32_16x16x32_bf16(wb[cur][ks], b0, acc[0], 0, 0, 0);
            acc[1] = __builtin_amdgcn_mfma_f32_16x16x32_bf16(wb[cur][ks], b1, acc[1], 0, 0, 0);
        }
    }

    if (OUT_CF) {
        #pragma unroll
        for (int r = 0; r < 4; ++r) {
            int co = co_w + l4 * 4 + r;
            float bv = bias[co];
            #pragma unroll
            for (int nb = 0; nb < 2; ++nb) {
                int p = y * 64 + x0 + nb * 16 + l15;
                size_t o = ((size_t)(b * CC + co)) * SP + p;
                outF[o] = acc[nb][r] + bv + resid[o];
            }
        }
    } else {
        int co0 = co_w + l4 * 4;
        float bv[4];
        #pragma unroll
        for (int r = 0; r < 4; ++r)
            bv[r] = bias[co0 + r] + (FUSE_TEMB ? temb[b * CC + co0 + r] : 0.f);
        #pragma unroll
        for (int nb = 0; nb < 2; ++nb) {
            int p = y * 64 + x0 + nb * 16 + l15;
            bf16x4 o;
            #pragma unroll
            for (int r = 0; r < 4; ++r)
                o[r] = (__bf16)(acc[nb][r] + bv[r]);
            *(bf16x4*)&outT[((size_t)(b * SP + p)) * CC + co0] = o;
        }
    }
}

// ---------------- fused cross-attention v13: latency-pipelined producer/consumer ----------------
// v12 post-mortem: all pipes <45%, per-iter wall ~5000cy vs ~900cy of work ->
// exposed HBM latency. Both the producer K-load and consumer V-load were
// issued ~100cy before use inside each barrier-delimited iteration, and K/V
// streams were fetched from HBM on every XCD (FETCH 34.9MB >> 12.6MB ideal).
// v13, zero new registers:
//  (1) code-motion software pipeline: producer re-issues K(i+2) right after
//      the MFMA that consumes K(i+1); consumer issues V(i+2) right after the
//      LDS-write drains st4. In-flight window ~2000+cy >> HBM 900cy.
//  (2) XCD swizzle: flatten grid to 512; w=bid>>3, b=(bid>>1)&3, s=bid&1.
//      All 64 w-blocks of one (b,s) read IDENTICAL K/V tiles and now share
//      one XCD's L2 (1MB working set < 4MB) -> 63/64 reads are L2 hits.
#define CT2 72    // ct2 row stride (bf16)
#define PBS 72    // Pb row stride (bf16)
// pool: ct2[2] 2x18432 B, Pb[2] 2x9216 B -> 55296 B
#define POOL_BYTES 55296
#define NIT (SP / TT / NS)   // 32

__global__ __launch_bounds__(512, 4) void attn_kernel(
    const __bf16* __restrict__ h1T, const __bf16* __restrict__ cmT,
    const __bf16* __restrict__ cm2, __bf16* __restrict__ parts)
{
    const int bid = blockIdx.x;
    const int w = bid >> 3;            // 64 values
    const int b = (bid >> 1) & 3;      // 4 values
    const int s = bid & 1;             // NS=2 values; (b,s) fixed per XCD
    const int tid = threadIdx.x;
    const int wid = tid >> 6;
    const int l = tid & 63, l15 = l & 15, l4 = l >> 4;

    __shared__ __align__(16) char pool[POOL_BYTES];
    __bf16* ct2p = (__bf16*)pool;               // 2 buffers of 9216 elems
    __bf16* Pbp  = (__bf16*)(pool + 36864);     // 2 buffers of 4608 elems
    __bf16* Otr  = (__bf16*)pool;               // epilogue alias

    const __bf16* h1Tb = h1T + (size_t)b * SP * CC;
    const __bf16* cmTb = cmT + (size_t)b * SP * CC;
    const __bf16* cm2b = cm2 + (size_t)b * CC * SP;

    if (wid < 4) {
        // ================= producer: QK^T + softmax =================
        const int pw = wid;   // owns 16 uv rows of each tile
        bf16x8 hfr[4][4];     // Q: 64h x 128c, register/AGPR-resident
        #pragma unroll
        for (int nt = 0; nt < 4; ++nt)
            #pragma unroll
            for (int ks = 0; ks < 4; ++ks)
                hfr[nt][ks] = *(const bf16x8*)&h1Tb[((size_t)((nt * 16 + l15) * WW + w)) * CC + ks * 32 + l4 * 8];

        bf16x8 afr[4];   // K fragments for the NEXT tile to produce

        // P(0) -> Pb[0], then issue K(1)
        {
            const int uv0 = s * TT;
            const __bf16* arow = cmTb + (size_t)(uv0 + 16 * pw + l15) * CC;
            bf16x8 a0[4];
            #pragma unroll
            for (int ks = 0; ks < 4; ++ks) a0[ks] = *(const bf16x8*)&arow[ks * 32 + l4 * 8];
            f32x4 s1[4];
            __builtin_amdgcn_s_setprio(1);
            #pragma unroll
            for (int nt = 0; nt < 4; ++nt) {
                s1[nt] = (f32x4){0.f, 0.f, 0.f, 0.f};
                #pragma unroll
                for (int ks = 0; ks < 4; ++ks)
                    s1[nt] = __builtin_amdgcn_mfma_f32_16x16x32_bf16(a0[ks], hfr[nt][ks], s1[nt], 0, 0, 0);
            }
            __builtin_amdgcn_s_setprio(0);
            // issue K(1) while softmax runs
            {
                const int uv1 = (NS + s) * TT;
                const __bf16* arow1 = cmTb + (size_t)(uv1 + 16 * pw + l15) * CC;
                #pragma unroll
                for (int ks = 0; ks < 4; ++ks) afr[ks] = *(const bf16x8*)&arow1[ks * 32 + l4 * 8];
            }
            #pragma unroll
            for (int r = 0; r < 4; ++r) {
                float e0 = fast_exp2(s1[0][r]), e1 = fast_exp2(s1[1][r]);
                float e2 = fast_exp2(s1[2][r]), e3 = fast_exp2(s1[3][r]);
                float sm = (e0 + e1) + (e2 + e3);
                sm = row16_sum(sm);
                float ri = 1.f / sm;
                s1[0][r] = e0 * ri; s1[1][r] = e1 * ri;
                s1[2][r] = e2 * ri; s1[3][r] = e3 * ri;
            }
            #pragma unroll
            for (int nt = 0; nt < 4; ++nt) {
                bf16x4 pk;
                pk[0] = (__bf16)s1[nt][0]; pk[1] = (__bf16)s1[nt][1];
                pk[2] = (__bf16)s1[nt][2]; pk[3] = (__bf16)s1[nt][3];
                *(bf16x4*)&Pbp[(nt * 16 + l15) * PBS + 16 * pw + l4 * 4] = pk;
            }
        }
        __syncthreads();   // #1: Pb[0] + ct2[0] ready

        for (int i = 0; i < NIT; ++i) {
            if (i < NIT - 1) {
                // afr holds K(i+1) (issued >= 1 iteration ago)
                f32x4 s1[4];
                __builtin_amdgcn_s_setprio(1);
                #pragma unroll
                for (int nt = 0; nt < 4; ++nt) {
                    s1[nt] = (f32x4){0.f, 0.f, 0.f, 0.f};
                    #pragma unroll
                    for (int ks = 0; ks < 4; ++ks)
                        s1[nt] = __builtin_amdgcn_mfma_f32_16x16x32_bf16(afr[ks], hfr[nt][ks], s1[nt], 0, 0, 0);
                }
                __builtin_amdgcn_s_setprio(0);
                // re-issue K(i+2) immediately after last use of afr
                if (i < NIT - 2) {
                    const int uv2 = ((i + 2) * NS + s) * TT;
                    const __bf16* arow = cmTb + (size_t)(uv2 + 16 * pw + l15) * CC;
                    #pragma unroll
                    for (int ks = 0; ks < 4; ++ks) afr[ks] = *(const bf16x8*)&arow[ks * 32 + l4 * 8];
                }
                #pragma unroll
                for (int r = 0; r < 4; ++r) {
                    float e0 = fast_exp2(s1[0][r]), e1 = fast_exp2(s1[1][r]);
                    float e2 = fast_exp2(s1[2][r]), e3 = fast_exp2(s1[3][r]);
                    float sm = (e0 + e1) + (e2 + e3);
                    sm = row16_sum(sm);
                    float ri = 1.f / sm;
                    s1[0][r] = e0 * ri; s1[1][r] = e1 * ri;
                    s1[2][r] = e2 * ri; s1[3][r] = e3 * ri;
                }
                __bf16* PbW = Pbp + ((i & 1) ^ 1) * 4608;
                #pragma unroll
                for (int nt = 0; nt < 4; ++nt) {
                    bf16x4 pk;
                    pk[0] = (__bf16)s1[nt][0]; pk[1] = (__bf16)s1[nt][1];
                    pk[2] = (__bf16)s1[nt][2]; pk[3] = (__bf16)s1[nt][3];
                    *(bf16x4*)&PbW[(nt * 16 + l15) * PBS + 16 * pw + l4 * 4] = pk;
                }
            }
            __syncthreads();   // per-iter barrier (matches consumer)
        }
    } else {
        // ================= consumer: PV accumulate =================
        const int cw = wid - 4;
        const int hB = (cw & 1) * 32;
        const int cB = (cw >> 1) * 64;
        const int tc = tid - 256;       // 0..255 within consumer group
        const int sc = tc >> 3;
        const int stc = tc & 7;

        f32x4 acc2[2][4];
        #pragma unroll
        for (int mb = 0; mb < 2; ++mb)
            #pragma unroll
            for (int nt = 0; nt < 4; ++nt) acc2[mb][nt] = (f32x4){0.f, 0.f, 0.f, 0.f};

        bf16x8 st4[4];   // V fragments for the NEXT tile to stage

        // stage ct2[0] directly, then issue V(1)
        {
            const int uv0 = s * TT;
            #pragma unroll
            for (int it = 0; it < 4; ++it) {
                int c = it * 32 + sc;
                *(bf16x8*)&ct2p[c * CT2 + stc * 8] =
                    *(const bf16x8*)&cm2b[(size_t)c * SP + uv0 + stc * 8];
            }
            const int uv1 = (NS + s) * TT;
            #pragma unroll
            for (int it = 0; it < 4; ++it) {
                int c = it * 32 + sc;
                st4[it] = *(const bf16x8*)&cm2b[(size_t)c * SP + uv1 + stc * 8];
            }
        }
        __syncthreads();   // #1: Pb[0] + ct2[0] ready

        for (int i = 0; i < NIT; ++i) {
            const int cur = i & 1;
            // consume tile i
            {
                const __bf16* PbR = Pbp + cur * 4608;
                const __bf16* ctR = ct2p + cur * 9216;
                bf16x8 pfr[2][2];
                #pragma unroll
                for (int mb = 0; mb < 2; ++mb)
                    #pragma unroll
                    for (int ks = 0; ks < 2; ++ks)
                        pfr[mb][ks] = *(const bf16x8*)&PbR[(hB + mb * 16 + l15) * PBS + ks * 32 + l4 * 8];
                bf16x8 bfr[4][2];
                #pragma unroll
                for (int nt = 0; nt < 4; ++nt)
                    #pragma unroll
                    for (int ks = 0; ks < 2; ++ks)
                        bfr[nt][ks] = *(const bf16x8*)&ctR[(cB + nt * 16 + l15) * CT2 + ks * 32 + l4 * 8];
                __builtin_amdgcn_s_setprio(1);
                #pragma unroll
                for (int mb = 0; mb < 2; ++mb)
                    #pragma unroll
                    for (int nt = 0; nt < 4; ++nt)
                        #pragma unroll
                        for (int ks = 0; ks < 2; ++ks)
                            acc2[mb][nt] = __builtin_amdgcn_mfma_f32_16x16x32_bf16(
                                pfr[mb][ks], bfr[nt][ks], acc2[mb][nt], 0, 0, 0);
                __builtin_amdgcn_s_setprio(0);
            }
            // write V(i+1) (in flight >= 1 iter) into the other LDS buffer,
            // then immediately issue V(i+2) into the drained st4 regs
            if (i < NIT - 1) {
                __bf16* ctW = ct2p + (cur ^ 1) * 9216;
                #pragma unroll
                for (int it = 0; it < 4; ++it) {
                    int c = it * 32 + sc;
                    *(bf16x8*)&ctW[c * CT2 + stc * 8] = st4[it];
                }
                if (i < NIT - 2) {
                    const int uv2 = ((i + 2) * NS + s) * TT;
                    #pragma unroll
                    for (int it = 0; it < 4; ++it) {
                        int c = it * 32 + sc;
                        st4[it] = *(const bf16x8*)&cm2b[(size_t)c * SP + uv2 + stc * 8];
                    }
                }
            }
            __syncthreads();   // per-iter barrier (matches producer)
        }

        // consumers hold the output: transpose-stage into LDS
        #pragma unroll
        for (int mb = 0; mb < 2; ++mb)
            #pragma unroll
            for (int nt = 0; nt < 4; ++nt)
                #pragma unroll
                for (int r = 0; r < 4; ++r)
                    Otr[(hB + mb * 16 + l4 * 4 + r) * 136 + cB + nt * 16 + l15] =
                        (__bf16)acc2[mb][nt][r];
    }

    __syncthreads();   // convergent: Otr complete
    __bf16* pO = parts + (size_t)s * PSZ;
    #pragma unroll
    for (int it = 0; it < 2; ++it) {
        int q = it * 512 + tid;
        int h = q >> 4, cc = q & 15;
        *(bf16x8*)&pO[((size_t)(b * SP + h * WW + w)) * CC + cc * 8] =
            *(const bf16x8*)&Otr[h * 136 + cc * 8];
    }
}

// ---------------- GN2 stats: h2 -> h2T bf16 + atomic group sums ----------------
__global__ __launch_bounds__(256) void gn2_stats_kernel(
    const __bf16* __restrict__ h1T, const __bf16* __restrict__ parts,
    const int* __restrict__ aim, const float* __restrict__ emb,
    __bf16* __restrict__ h2T, float* __restrict__ gstat)
{
    const int pb = blockIdx.x, b = blockIdx.y;
    const int tid = threadIdx.x;
    const int c4 = tid & 31;
    const float4 ev = *(const float4*)&emb[aim[b] * CC + c4 * 4];
    float s = 0.f, s2 = 0.f;
    for (int it = 0; it < 8; ++it) {
        int prow = it * 8 + (tid >> 5);
        size_t base = ((size_t)(b * SP + pb * 64 + prow)) * CC + c4 * 4;
        bf16x4 hv = *(const bf16x4*)&h1T[base];
        float v0 = (float)hv[0] + ev.x;
        float v1 = (float)hv[1] + ev.y;
        float v2 = (float)hv[2] + ev.z;
        float v3 = (float)hv[3] + ev.w;
        #pragma unroll
        for (int k = 0; k < NS; ++k) {
            bf16x4 a = *(const bf16x4*)&parts[(size_t)k * PSZ + base];
            v0 += (float)a[0]; v1 += (float)a[1];
            v2 += (float)a[2]; v3 += (float)a[3];
        }
        bf16x4 o;
        o[0] = (__bf16)v0; o[1] = (__bf16)v1;
        o[2] = (__bf16)v2; o[3] = (__bf16)v3;
        *(bf16x4*)&h2T[base] = o;
        s += v0 + v1 + v2 + v3;
        s2 += v0 * v0 + v1 * v1 + v2 * v2 + v3 * v3;
    }
    s  += __shfl_down(s,  32, 64);
    s2 += __shfl_down(s2, 32, 64);
    __shared__ float ls[4][32][2];
    const int wv = tid >> 6, ll = tid & 63;
    if (ll < 32) { ls[wv][ll][0] = s; ls[wv][ll][1] = s2; }
    __syncthreads();
    if (tid < 32) {
        float S = ls[0][tid][0] + ls[1][tid][0] + ls[2][tid][0] + ls[3][tid][0];
        float S2 = ls[0][tid][1] + ls[1][tid][1] + ls[2][tid][1] + ls[3][tid][1];
        atomicAdd(&gstat[(b * NG + tid) * 2], S);
        atomicAdd(&gstat[(b * NG + tid) * 2 + 1], S2);
    }
}

extern "C" void kernel_launch(void* const* d_in, const int* in_sizes, int n_in,
                              void* d_out, int out_size, void* d_ws, size_t ws_size,
                              hipStream_t stream)
{
    const float* x     = (const float*)d_in[0];
    const float* t     = (const float*)d_in[1];
    const int*   aim   = (const int*)  d_in[2];
    const float* cond  = (const float*)d_in[3];
    const float* gn1s  = (const float*)d_in[4];
    const float* gn1b  = (const float*)d_in[5];
    const float* c1w   = (const float*)d_in[6];
    const float* c1b   = (const float*)d_in[7];
    const float* mlpw  = (const float*)d_in[8];
    const float* mlpb  = (const float*)d_in[9];
    const float* cw    = (const float*)d_in[10];
    const float* cb    = (const float*)d_in[11];
    const float* gn2s  = (const float*)d_in[12];
    const float* gn2b  = (const float*)d_in[13];
    const float* c2w   = (const float*)d_in[14];
    const float* c2b   = (const float*)d_in[15];
    const float* emb   = (const float*)d_in[16];
    float* out = (float*)d_out;
    float* ws = (float*)d_ws;

    // float-offset workspace map
    __bf16* aT    = (__bf16*)ws;                  // [0, 1048576)
    __bf16* h1T   = (__bf16*)(ws + 1048576);
    __bf16* cmT   = (__bf16*)(ws + 2097152);      // h2T after attn
    __bf16* cm2   = (__bf16*)(ws + 3145728);
    __bf16* parts = (__bf16*)(ws + 4194304);      // 2 partials
    __bf16* wt    = (__bf16*)(ws + 6291456);
    float*  tembw = ws + 6438912;
    float*  gstat = ws + 6439424;                 // 256 floats
    __bf16* h2T   = cmT;

    prep_kernel<<<dim3(410), dim3(256), 0, stream>>>(
        x, gn1s, gn1b, aT, c1w, c2w, wt, t, mlpw, mlpb, tembw,
        cond, cw, cb, cmT, cm2);
    hipMemsetAsync(gstat, 0, 256 * sizeof(float), stream);
    conv_mfma_kernel<true, false, false><<<dim3(256, BB), dim3(256), 0, stream>>>(
        aT, wt, c1b, tembw, nullptr, h1T, nullptr, nullptr, nullptr, nullptr);
    attn_kernel<<<dim3(WW * BB * NS), dim3(512), 0, stream>>>(h1T, cmT, cm2, parts);
    gn2_stats_kernel<<<dim3(64, BB), dim3(256), 0, stream>>>(h1T, parts, aim, emb, h2T, gstat);
    conv_mfma_kernel<false, true, true><<<dim3(256, BB), dim3(256), 0, stream>>>(
        h2T, wt + (size_t)9 * 16384, c2b, nullptr, x, nullptr, out, gstat, gn2s, gn2b);
}

// Round 9
// 209.030 us; speedup vs baseline: 1.3830x; 1.0085x over previous
//
#include <hip/hip_runtime.h>
#include <cmath>

#define BB 4
#define CC 128
#define HH 64
#define WW 64
#define SP 4096   // H*W
#define NG 32     // groups
#define TT 64     // attention uv-tile width
#define NS 2      // attention uv split factor
#define PSZ ((size_t)BB * SP * CC)   // partial tensor elements

typedef __bf16 bf16x8 __attribute__((ext_vector_type(8)));
typedef __bf16 bf16x4 __attribute__((ext_vector_type(4)));
typedef float  f32x4  __attribute__((ext_vector_type(4)));

__device__ __forceinline__ float silu_f(float v) {
    return v / (1.f + __expf(-v));
}

__device__ __forceinline__ float fast_exp2(float x) {
    return exp2f(x);   // v_exp_f32
}

// DPP-based add of lane^mask partner within each row of 16 (VALU pipe, not LDS).
template<int CTRL>
__device__ __forceinline__ float dpp_add(float v) {
    int m = __builtin_amdgcn_update_dpp(0, __float_as_int(v), CTRL, 0xF, 0xF, true);
    return v + __int_as_float(m);
}
// 16-lane sum (over lane bits 0..3): xor1, xor2 (quad_perm), then after quads are
// uniform, row_half_mirror (= +quad^1) and row_mirror (= +quad^3) complete the sum.
__device__ __forceinline__ float row16_sum(float v) {
    v = dpp_add<0xB1>(v);    // quad_perm [1,0,3,2]  : + lane^1
    v = dpp_add<0x4E>(v);    // quad_perm [2,3,0,1]  : + lane^2
    v = dpp_add<0x141>(v);   // row_half_mirror      : + other quad in half
    v = dpp_add<0x140>(v);   // row_mirror           : + other half of row
    return v;
}

// ================= merged prep kernel (slim LDS) =================
__global__ __launch_bounds__(256) void prep_kernel(
    const float* __restrict__ x, const float* __restrict__ gn1s,
    const float* __restrict__ gn1b, __bf16* __restrict__ aT,
    const float* __restrict__ c1w, const float* __restrict__ c2w,
    __bf16* __restrict__ wt,
    const float* __restrict__ t, const float* __restrict__ mlpw,
    const float* __restrict__ mlpb, float* __restrict__ tembw,
    const float* __restrict__ cond, const float* __restrict__ cw,
    const float* __restrict__ cb, __bf16* __restrict__ cmT,
    __bf16* __restrict__ cm2)
{
    __shared__ __align__(16) char pool[18432];
    __shared__ float rs[4], rs2[4], mean_s, inv_s;
    const int blk = blockIdx.x;
    const int tid = threadIdx.x;

    if (blk < 128) {
        // ---- GN1 two-pass ----
        const int b = blk >> 5, g = blk & 31;
        const float* p = x + (size_t)blk * 16384;
        float s = 0.f, s2 = 0.f;
        for (int it = 0; it < 16; ++it) {
            int q = it * 256 + tid;
            float4 v = *(const float4*)&p[q * 4];
            s += v.x + v.y + v.z + v.w;
            s2 += v.x * v.x + v.y * v.y + v.z * v.z + v.w * v.w;
        }
        #pragma unroll
        for (int off = 32; off >= 1; off >>= 1) {
            s  += __shfl_down(s,  off, 64);
            s2 += __shfl_down(s2, off, 64);
        }
        const int wid = tid >> 6;
        if ((tid & 63) == 0) { rs[wid] = s; rs2[wid] = s2; }
        __syncthreads();
        if (tid == 0) {
            float S = rs[0] + rs[1] + rs[2] + rs[3];
            float S2 = rs2[0] + rs2[1] + rs2[2] + rs2[3];
            float m = S * (1.f / 16384.f);
            float var = S2 * (1.f / 16384.f) - m * m;
            mean_s = m;
            inv_s = rsqrtf(var + 1e-5f);
        }
        __syncthreads();
        const float m = mean_s, inv = inv_s;
        float sc[4], bi[4];
        #pragma unroll
        for (int j = 0; j < 4; ++j) { sc[j] = gn1s[g * 4 + j]; bi[j] = gn1b[g * 4 + j]; }
        for (int it = 0; it < 16; ++it) {
            int pp = it * 256 + tid;
            bf16x4 o;
            #pragma unroll
            for (int j = 0; j < 4; ++j)
                o[j] = (__bf16)silu_f((p[j * 4096 + pp] - m) * inv * sc[j] + bi[j]);
            *(bf16x4*)&aT[((size_t)(b * SP + pp)) * CC + g * 4] = o;
        }
    } else if (blk < 146) {
        // ---- weight transpose ----
        const int idx = blk - 128;
        const int wsel = idx / 9, tap = idx % 9;
        const float* src = wsel ? c2w : c1w;
        __bf16* dst = wt + (size_t)wsel * 9 * 16384 + (size_t)tap * 16384;
        for (int it = 0; it < 64; ++it) {
            int q = it * 256 + tid;
            dst[q] = (__bf16)src[(size_t)q * 9 + tap];
        }
    } else if (blk < 154) {
        // ---- temb MLP ----
        const int cog = blk - 146;
        float* st = (float*)pool;
        for (int it = 0; it < 8; ++it) {
            int q = it * 256 + tid;
            st[q] = silu_f(t[q]);
        }
        __syncthreads();
        const int col = tid >> 4, seg = tid & 15;
        const float* wr = mlpw + (size_t)(cog * 16 + col) * 512 + seg * 32;
        float acc[4] = {0.f, 0.f, 0.f, 0.f};
        #pragma unroll
        for (int k8 = 0; k8 < 8; ++k8) {
            float4 wv = *(const float4*)&wr[k8 * 4];
            #pragma unroll
            for (int j = 0; j < 4; ++j) {
                int k = seg * 32 + k8 * 4 + j;
                float w4 = (&wv.x)[j];
                acc[0] += st[0 * 512 + k] * w4;
                acc[1] += st[1 * 512 + k] * w4;
                acc[2] += st[2 * 512 + k] * w4;
                acc[3] += st[3 * 512 + k] * w4;
            }
        }
        #pragma unroll
        for (int o = 1; o < 16; o <<= 1) {
            #pragma unroll
            for (int b4 = 0; b4 < 4; ++b4)
                acc[b4] += __shfl_xor(acc[b4], o, 64);
        }
        if (seg == 0) {
            float bv = mlpb[cog * 16 + col];
            #pragma unroll
            for (int b4 = 0; b4 < 4; ++b4)
                tembw[b4 * 128 + cog * 16 + col] = acc[b4] + bv;
        }
    } else {
        // ---- 1x1 conv MFMA ----
        const int pblk = blk - 154;
        const int b = pblk >> 6;
        const int p0 = (pblk & 63) * 64;
        const int l = tid & 63, wv = tid >> 6;
        const int l15 = l & 15, l4 = l >> 4;
        const int mB = wv * 32;

        __bf16* XT = (__bf16*)pool;

        for (int it = 0; it < 32; ++it) {
            int q = it * 256 + tid;
            float v = cond[((size_t)(b * CC + (q >> 6))) * SP + p0 + (q & 63)];
            XT[(q & 63) * 136 + (q >> 6)] = (__bf16)v;
        }
        __syncthreads();

        f32x4 acc[2][4];
        #pragma unroll
        for (int mb = 0; mb < 2; ++mb)
            #pragma unroll
            for (int nt = 0; nt < 4; ++nt) acc[mb][nt] = (f32x4){0.f, 0.f, 0.f, 0.f};

        #pragma unroll
        for (int ks = 0; ks < 4; ++ks) {
            bf16x8 bfr[4];
            #pragma unroll
            for (int nt = 0; nt < 4; ++nt)
                bfr[nt] = *(const bf16x8*)&XT[(nt * 16 + l15) * 136 + ks * 32 + l4 * 8];
            #pragma unroll
            for (int mb = 0; mb < 2; ++mb) {
                const float* wrow = cw + (size_t)(mB + mb * 16 + l15) * 128 + ks * 32 + l4 * 8;
                float4 wa = *(const float4*)wrow;
                float4 wb4 = *(const float4*)(wrow + 4);
                bf16x8 afr;
                afr[0] = (__bf16)wa.x; afr[1] = (__bf16)wa.y;
                afr[2] = (__bf16)wa.z; afr[3] = (__bf16)wa.w;
                afr[4] = (__bf16)wb4.x; afr[5] = (__bf16)wb4.y;
                afr[6] = (__bf16)wb4.z; afr[7] = (__bf16)wb4.w;
                #pragma unroll
                for (int nt = 0; nt < 4; ++nt)
                    acc[mb][nt] = __builtin_amdgcn_mfma_f32_16x16x32_bf16(afr, bfr[nt], acc[mb][nt], 0, 0, 0);
            }
        }

        // scale = log2(e)/sqrt(128): folds the softmax temperature AND the
        // exp->exp2 conversion into the attention K operand (cmT is only ever
        // consumed as the QK^T A-operand in attn_kernel).
        const float scl = 0.12751743f;
        #pragma unroll
        for (int mb = 0; mb < 2; ++mb) {
            int co0 = mB + mb * 16 + l4 * 4;
            float bv[4];
            #pragma unroll
            for (int r = 0; r < 4; ++r) bv[r] = cb[co0 + r];
            #pragma unroll
            for (int nt = 0; nt < 4; ++nt) {
                int p = p0 + nt * 16 + l15;
                bf16x4 o;
                #pragma unroll
                for (int r = 0; r < 4; ++r)
                    o[r] = (__bf16)((acc[mb][nt][r] + bv[r]) * scl);
                *(bf16x4*)&cmT[((size_t)(b * SP + p)) * CC + co0] = o;
            }
        }
        __syncthreads();
        __bf16* O2 = (__bf16*)pool;
        #pragma unroll
        for (int mb = 0; mb < 2; ++mb) {
            int co0 = mB + mb * 16 + l4 * 4;
            #pragma unroll
            for (int r = 0; r < 4; ++r) {
                float bv = cb[co0 + r];
                #pragma unroll
                for (int nt = 0; nt < 4; ++nt)
                    O2[(co0 + r) * 72 + nt * 16 + l15] = (__bf16)(acc[mb][nt][r] + bv);
            }
        }
        __syncthreads();
        #pragma unroll
        for (int it = 0; it < 4; ++it) {
            int q = it * 256 + tid;
            int co = q >> 3, pc = q & 7;
            *(bf16x8*)&cm2[((size_t)(b * CC + co)) * SP + p0 + pc * 8] =
                *(const bf16x8*)&O2[co * 72 + pc * 8];
        }
    }
}

// ---------------- 3x3 conv v2: 512-thread blocks, all 128 co per block ----------------
// Old tiling (256thr, 1y x 32x x 64co, coh split) staged+activated every input
// element 6.4x per output. v2: 8 waves cover all 128 co of the same 32 x-slice
// -> staging bytes and fused-GN SiLU work per output halve; grid 1024 -> 512.
template<bool FUSE_TEMB, bool OUT_CF, bool FUSE_GN>
__global__ __launch_bounds__(512, 4) void conv_mfma_kernel(
    const __bf16* __restrict__ inT, const __bf16* __restrict__ wt,
    const float* __restrict__ bias, const float* __restrict__ temb,
    const float* __restrict__ resid, __bf16* __restrict__ outT,
    float* __restrict__ outF, const float* __restrict__ gstat,
    const float* __restrict__ gn_s, const float* __restrict__ gn_b)
{
    const int y   = blockIdx.x >> 1;
    const int xh2 = blockIdx.x & 1;
    const int x0  = xh2 * 32;
    const int b   = blockIdx.y;
    const int tid = threadIdx.x;
    const int l = tid & 63, wv = tid >> 6;
    const int l15 = l & 15, l4 = l >> 4;
    const int co_w = wv * 16;            // 8 waves -> co 0..127

    __shared__ __bf16 inS[3 * 16 * 34 * 8];   // 26 KB
    __shared__ float af[128], bfp[128];

    if (FUSE_GN) {
        if (tid < 128) {
            int g = tid >> 2;
            float S = gstat[(b * NG + g) * 2], S2 = gstat[(b * NG + g) * 2 + 1];
            float m = S * (1.f / 16384.f);
            float var = S2 * (1.f / 16384.f) - m * m;
            float inv = rsqrtf(var + 1e-5f);
            float a = inv * gn_s[tid];
            af[tid] = a;
            bfp[tid] = gn_b[tid] - m * a;
        }
        __syncthreads();
    }

    const __bf16* inTb = inT + (size_t)b * SP * CC;
    for (int q = tid; q < 3 * 34 * 16; q += 512) {
        int cc = q & 15;
        int t2 = q >> 4;
        int xs = t2 % 34;
        int r  = t2 / 34;
        int yy = y + r - 1;
        int xg = x0 + xs - 1;
        bf16x8 v;
        if (((unsigned)yy < 64u) && ((unsigned)xg < 64u)) {
            bf16x8 raw = *(const bf16x8*)&inTb[((size_t)(yy * 64 + xg)) * CC + cc * 8];
            if (FUSE_GN) {
                #pragma unroll
                for (int j = 0; j < 8; ++j) {
                    int c = cc * 8 + j;
                    v[j] = (__bf16)silu_f((float)raw[j] * af[c] + bfp[c]);
                }
            } else {
                v = raw;
            }
        } else {
            #pragma unroll
            for (int j = 0; j < 8; ++j) v[j] = (__bf16)0.f;
        }
        *(bf16x8*)&inS[((r * 16 + cc) * 34 + xs) * 8] = v;
    }
    __syncthreads();

    f32x4 acc[2];
    acc[0] = (f32x4){0.f, 0.f, 0.f, 0.f};
    acc[1] = (f32x4){0.f, 0.f, 0.f, 0.f};

    const __bf16* wp = wt + (size_t)(co_w + l15) * 128 + l4 * 8;
    bf16x8 wb[2][4];
    #pragma unroll
    for (int ks = 0; ks < 4; ++ks)
        wb[0][ks] = *(const bf16x8*)(wp + ks * 32);

    #pragma unroll
    for (int tap = 0; tap < 9; ++tap) {
        const int cur = tap & 1, nxt = cur ^ 1;
        if (tap < 8) {
            #pragma unroll
            for (int ks = 0; ks < 4; ++ks)
                wb[nxt][ks] = *(const bf16x8*)(wp + (tap + 1) * 16384 + ks * 32);
        }
        const int rr = tap / 3, dx = tap % 3;
        #pragma unroll
        for (int ks = 0; ks < 4; ++ks) {
            const __bf16* rb = &inS[((rr * 16 + ks * 4 + l4) * 34) * 8];
            bf16x8 b0 = *(const bf16x8*)&rb[(dx + l15) * 8];
            bf16x8 b1 = *(const bf16x8*)&rb[(16 + dx + l15) * 8];
            acc[0] = __builtin_amdgcn_mfma_f32_16x16x32_bf16(wb[cur][ks], b0, acc[0], 0, 0, 0);
            acc[1] = __builtin_amdgcn_mfma_f32_16x16x32_bf16(wb[cur][ks], b1, acc[1], 0, 0, 0);
        }
    }

    if (OUT_CF) {
        #pragma unroll
        for (int r = 0; r < 4; ++r) {
            int co = co_w + l4 * 4 + r;
            float bv = bias[co];
            #pragma unroll
            for (int nb = 0; nb < 2; ++nb) {
                int p = y * 64 + x0 + nb * 16 + l15;
                size_t o = ((size_t)(b * CC + co)) * SP + p;
                outF[o] = acc[nb][r] + bv + resid[o];
            }
        }
    } else {
        int co0 = co_w + l4 * 4;
        float bv[4];
        #pragma unroll
        for (int r = 0; r < 4; ++r)
            bv[r] = bias[co0 + r] + (FUSE_TEMB ? temb[b * CC + co0 + r] : 0.f);
        #pragma unroll
        for (int nb = 0; nb < 2; ++nb) {
            int p = y * 64 + x0 + nb * 16 + l15;
            bf16x4 o;
            #pragma unroll
            for (int r = 0; r < 4; ++r)
                o[r] = (__bf16)(acc[nb][r] + bv[r]);
            *(bf16x4*)&outT[((size_t)(b * SP + p)) * CC + co0] = o;
        }
    }
}

// ---------------- fused cross-attention v13: latency-pipelined producer/consumer ----------------
// (unchanged from round 8 — FETCH 8.3MB, dur 57.6us, MfmaUtil at floor)
#define CT2 72    // ct2 row stride (bf16)
#define PBS 72    // Pb row stride (bf16)
// pool: ct2[2] 2x18432 B, Pb[2] 2x9216 B -> 55296 B
#define POOL_BYTES 55296
#define NIT (SP / TT / NS)   // 32

__global__ __launch_bounds__(512, 4) void attn_kernel(
    const __bf16* __restrict__ h1T, const __bf16* __restrict__ cmT,
    const __bf16* __restrict__ cm2, __bf16* __restrict__ parts)
{
    const int bid = blockIdx.x;
    const int w = bid >> 3;            // 64 values
    const int b = (bid >> 1) & 3;      // 4 values
    const int s = bid & 1;             // NS=2 values; (b,s) fixed per XCD
    const int tid = threadIdx.x;
    const int wid = tid >> 6;
    const int l = tid & 63, l15 = l & 15, l4 = l >> 4;

    __shared__ __align__(16) char pool[POOL_BYTES];
    __bf16* ct2p = (__bf16*)pool;               // 2 buffers of 9216 elems
    __bf16* Pbp  = (__bf16*)(pool + 36864);     // 2 buffers of 4608 elems
    __bf16* Otr  = (__bf16*)pool;               // epilogue alias

    const __bf16* h1Tb = h1T + (size_t)b * SP * CC;
    const __bf16* cmTb = cmT + (size_t)b * SP * CC;
    const __bf16* cm2b = cm2 + (size_t)b * CC * SP;

    if (wid < 4) {
        // ================= producer: QK^T + softmax =================
        const int pw = wid;   // owns 16 uv rows of each tile
        bf16x8 hfr[4][4];     // Q: 64h x 128c, register/AGPR-resident
        #pragma unroll
        for (int nt = 0; nt < 4; ++nt)
            #pragma unroll
            for (int ks = 0; ks < 4; ++ks)
                hfr[nt][ks] = *(const bf16x8*)&h1Tb[((size_t)((nt * 16 + l15) * WW + w)) * CC + ks * 32 + l4 * 8];

        bf16x8 afr[4];   // K fragments for the NEXT tile to produce

        // P(0) -> Pb[0], then issue K(1)
        {
            const int uv0 = s * TT;
            const __bf16* arow = cmTb + (size_t)(uv0 + 16 * pw + l15) * CC;
            bf16x8 a0[4];
            #pragma unroll
            for (int ks = 0; ks < 4; ++ks) a0[ks] = *(const bf16x8*)&arow[ks * 32 + l4 * 8];
            f32x4 s1[4];
            __builtin_amdgcn_s_setprio(1);
            #pragma unroll
            for (int nt = 0; nt < 4; ++nt) {
                s1[nt] = (f32x4){0.f, 0.f, 0.f, 0.f};
                #pragma unroll
                for (int ks = 0; ks < 4; ++ks)
                    s1[nt] = __builtin_amdgcn_mfma_f32_16x16x32_bf16(a0[ks], hfr[nt][ks], s1[nt], 0, 0, 0);
            }
            __builtin_amdgcn_s_setprio(0);
            // issue K(1) while softmax runs
            {
                const int uv1 = (NS + s) * TT;
                const __bf16* arow1 = cmTb + (size_t)(uv1 + 16 * pw + l15) * CC;
                #pragma unroll
                for (int ks = 0; ks < 4; ++ks) afr[ks] = *(const bf16x8*)&arow1[ks * 32 + l4 * 8];
            }
            #pragma unroll
            for (int r = 0; r < 4; ++r) {
                float e0 = fast_exp2(s1[0][r]), e1 = fast_exp2(s1[1][r]);
                float e2 = fast_exp2(s1[2][r]), e3 = fast_exp2(s1[3][r]);
                float sm = (e0 + e1) + (e2 + e3);
                sm = row16_sum(sm);
                float ri = 1.f / sm;
                s1[0][r] = e0 * ri; s1[1][r] = e1 * ri;
                s1[2][r] = e2 * ri; s1[3][r] = e3 * ri;
            }
            #pragma unroll
            for (int nt = 0; nt < 4; ++nt) {
                bf16x4 pk;
                pk[0] = (__bf16)s1[nt][0]; pk[1] = (__bf16)s1[nt][1];
                pk[2] = (__bf16)s1[nt][2]; pk[3] = (__bf16)s1[nt][3];
                *(bf16x4*)&Pbp[(nt * 16 + l15) * PBS + 16 * pw + l4 * 4] = pk;
            }
        }
        __syncthreads();   // #1: Pb[0] + ct2[0] ready

        for (int i = 0; i < NIT; ++i) {
            if (i < NIT - 1) {
                // afr holds K(i+1) (issued >= 1 iteration ago)
                f32x4 s1[4];
                __builtin_amdgcn_s_setprio(1);
                #pragma unroll
                for (int nt = 0; nt < 4; ++nt) {
                    s1[nt] = (f32x4){0.f, 0.f, 0.f, 0.f};
                    #pragma unroll
                    for (int ks = 0; ks < 4; ++ks)
                        s1[nt] = __builtin_amdgcn_mfma_f32_16x16x32_bf16(afr[ks], hfr[nt][ks], s1[nt], 0, 0, 0);
                }
                __builtin_amdgcn_s_setprio(0);
                // re-issue K(i+2) immediately after last use of afr
                if (i < NIT - 2) {
                    const int uv2 = ((i + 2) * NS + s) * TT;
                    const __bf16* arow = cmTb + (size_t)(uv2 + 16 * pw + l15) * CC;
                    #pragma unroll
                    for (int ks = 0; ks < 4; ++ks) afr[ks] = *(const bf16x8*)&arow[ks * 32 + l4 * 8];
                }
                #pragma unroll
                for (int r = 0; r < 4; ++r) {
                    float e0 = fast_exp2(s1[0][r]), e1 = fast_exp2(s1[1][r]);
                    float e2 = fast_exp2(s1[2][r]), e3 = fast_exp2(s1[3][r]);
                    float sm = (e0 + e1) + (e2 + e3);
                    sm = row16_sum(sm);
                    float ri = 1.f / sm;
                    s1[0][r] = e0 * ri; s1[1][r] = e1 * ri;
                    s1[2][r] = e2 * ri; s1[3][r] = e3 * ri;
                }
                __bf16* PbW = Pbp + ((i & 1) ^ 1) * 4608;
                #pragma unroll
                for (int nt = 0; nt < 4; ++nt) {
                    bf16x4 pk;
                    pk[0] = (__bf16)s1[nt][0]; pk[1] = (__bf16)s1[nt][1];
                    pk[2] = (__bf16)s1[nt][2]; pk[3] = (__bf16)s1[nt][3];
                    *(bf16x4*)&PbW[(nt * 16 + l15) * PBS + 16 * pw + l4 * 4] = pk;
                }
            }
            __syncthreads();   // per-iter barrier (matches consumer)
        }
    } else {
        // ================= consumer: PV accumulate =================
        const int cw = wid - 4;
        const int hB = (cw & 1) * 32;
        const int cB = (cw >> 1) * 64;
        const int tc = tid - 256;       // 0..255 within consumer group
        const int sc = tc >> 3;
        const int stc = tc & 7;

        f32x4 acc2[2][4];
        #pragma unroll
        for (int mb = 0; mb < 2; ++mb)
            #pragma unroll
            for (int nt = 0; nt < 4; ++nt) acc2[mb][nt] = (f32x4){0.f, 0.f, 0.f, 0.f};

        bf16x8 st4[4];   // V fragments for the NEXT tile to stage

        // stage ct2[0] directly, then issue V(1)
        {
            const int uv0 = s * TT;
            #pragma unroll
            for (int it = 0; it < 4; ++it) {
                int c = it * 32 + sc;
                *(bf16x8*)&ct2p[c * CT2 + stc * 8] =
                    *(const bf16x8*)&cm2b[(size_t)c * SP + uv0 + stc * 8];
            }
            const int uv1 = (NS + s) * TT;
            #pragma unroll
            for (int it = 0; it < 4; ++it) {
                int c = it * 32 + sc;
                st4[it] = *(const bf16x8*)&cm2b[(size_t)c * SP + uv1 + stc * 8];
            }
        }
        __syncthreads();   // #1: Pb[0] + ct2[0] ready

        for (int i = 0; i < NIT; ++i) {
            const int cur = i & 1;
            // consume tile i
            {
                const __bf16* PbR = Pbp + cur * 4608;
                const __bf16* ctR = ct2p + cur * 9216;
                bf16x8 pfr[2][2];
                #pragma unroll
                for (int mb = 0; mb < 2; ++mb)
                    #pragma unroll
                    for (int ks = 0; ks < 2; ++ks)
                        pfr[mb][ks] = *(const bf16x8*)&PbR[(hB + mb * 16 + l15) * PBS + ks * 32 + l4 * 8];
                bf16x8 bfr[4][2];
                #pragma unroll
                for (int nt = 0; nt < 4; ++nt)
                    #pragma unroll
                    for (int ks = 0; ks < 2; ++ks)
                        bfr[nt][ks] = *(const bf16x8*)&ctR[(cB + nt * 16 + l15) * CT2 + ks * 32 + l4 * 8];
                __builtin_amdgcn_s_setprio(1);
                #pragma unroll
                for (int mb = 0; mb < 2; ++mb)
                    #pragma unroll
                    for (int nt = 0; nt < 4; ++nt)
                        #pragma unroll
                        for (int ks = 0; ks < 2; ++ks)
                            acc2[mb][nt] = __builtin_amdgcn_mfma_f32_16x16x32_bf16(
                                pfr[mb][ks], bfr[nt][ks], acc2[mb][nt], 0, 0, 0);
                __builtin_amdgcn_s_setprio(0);
            }
            // write V(i+1) (in flight >= 1 iter) into the other LDS buffer,
            // then immediately issue V(i+2) into the drained st4 regs
            if (i < NIT - 1) {
                __bf16* ctW = ct2p + (cur ^ 1) * 9216;
                #pragma unroll
                for (int it = 0; it < 4; ++it) {
                    int c = it * 32 + sc;
                    *(bf16x8*)&ctW[c * CT2 + stc * 8] = st4[it];
                }
                if (i < NIT - 2) {
                    const int uv2 = ((i + 2) * NS + s) * TT;
                    #pragma unroll
                    for (int it = 0; it < 4; ++it) {
                        int c = it * 32 + sc;
                        st4[it] = *(const bf16x8*)&cm2b[(size_t)c * SP + uv2 + stc * 8];
                    }
                }
            }
            __syncthreads();   // per-iter barrier (matches producer)
        }

        // consumers hold the output: transpose-stage into LDS
        #pragma unroll
        for (int mb = 0; mb < 2; ++mb)
            #pragma unroll
            for (int nt = 0; nt < 4; ++nt)
                #pragma unroll
                for (int r = 0; r < 4; ++r)
                    Otr[(hB + mb * 16 + l4 * 4 + r) * 136 + cB + nt * 16 + l15] =
                        (__bf16)acc2[mb][nt][r];
    }

    __syncthreads();   // convergent: Otr complete
    __bf16* pO = parts + (size_t)s * PSZ;
    #pragma unroll
    for (int it = 0; it < 2; ++it) {
        int q = it * 512 + tid;
        int h = q >> 4, cc = q & 15;
        *(bf16x8*)&pO[((size_t)(b * SP + h * WW + w)) * CC + cc * 8] =
            *(const bf16x8*)&Otr[h * 136 + cc * 8];
    }
}

// ---------------- GN2 stats: h2 -> h2T bf16 + atomic group sums ----------------
__global__ __launch_bounds__(256) void gn2_stats_kernel(
    const __bf16* __restrict__ h1T, const __bf16* __restrict__ parts,
    const int* __restrict__ aim, const float* __restrict__ emb,
    __bf16* __restrict__ h2T, float* __restrict__ gstat)
{
    const int pb = blockIdx.x, b = blockIdx.y;
    const int tid = threadIdx.x;
    const int c4 = tid & 31;
    const float4 ev = *(const float4*)&emb[aim[b] * CC + c4 * 4];
    float s = 0.f, s2 = 0.f;
    for (int it = 0; it < 8; ++it) {
        int prow = it * 8 + (tid >> 5);
        size_t base = ((size_t)(b * SP + pb * 64 + prow)) * CC + c4 * 4;
        bf16x4 hv = *(const bf16x4*)&h1T[base];
        float v0 = (float)hv[0] + ev.x;
        float v1 = (float)hv[1] + ev.y;
        float v2 = (float)hv[2] + ev.z;
        float v3 = (float)hv[3] + ev.w;
        #pragma unroll
        for (int k = 0; k < NS; ++k) {
            bf16x4 a = *(const bf16x4*)&parts[(size_t)k * PSZ + base];
            v0 += (float)a[0]; v1 += (float)a[1];
            v2 += (float)a[2]; v3 += (float)a[3];
        }
        bf16x4 o;
        o[0] = (__bf16)v0; o[1] = (__bf16)v1;
        o[2] = (__bf16)v2; o[3] = (__bf16)v3;
        *(bf16x4*)&h2T[base] = o;
        s += v0 + v1 + v2 + v3;
        s2 += v0 * v0 + v1 * v1 + v2 * v2 + v3 * v3;
    }
    s  += __shfl_down(s,  32, 64);
    s2 += __shfl_down(s2, 32, 64);
    __shared__ float ls[4][32][2];
    const int wv = tid >> 6, ll = tid & 63;
    if (ll < 32) { ls[wv][ll][0] = s; ls[wv][ll][1] = s2; }
    __syncthreads();
    if (tid < 32) {
        float S = ls[0][tid][0] + ls[1][tid][0] + ls[2][tid][0] + ls[3][tid][0];
        float S2 = ls[0][tid][1] + ls[1][tid][1] + ls[2][tid][1] + ls[3][tid][1];
        atomicAdd(&gstat[(b * NG + tid) * 2], S);
        atomicAdd(&gstat[(b * NG + tid) * 2 + 1], S2);
    }
}

extern "C" void kernel_launch(void* const* d_in, const int* in_sizes, int n_in,
                              void* d_out, int out_size, void* d_ws, size_t ws_size,
                              hipStream_t stream)
{
    const float* x     = (const float*)d_in[0];
    const float* t     = (const float*)d_in[1];
    const int*   aim   = (const int*)  d_in[2];
    const float* cond  = (const float*)d_in[3];
    const float* gn1s  = (const float*)d_in[4];
    const float* gn1b  = (const float*)d_in[5];
    const float* c1w   = (const float*)d_in[6];
    const float* c1b   = (const float*)d_in[7];
    const float* mlpw  = (const float*)d_in[8];
    const float* mlpb  = (const float*)d_in[9];
    const float* cw    = (const float*)d_in[10];
    const float* cb    = (const float*)d_in[11];
    const float* gn2s  = (const float*)d_in[12];
    const float* gn2b  = (const float*)d_in[13];
    const float* c2w   = (const float*)d_in[14];
    const float* c2b   = (const float*)d_in[15];
    const float* emb   = (const float*)d_in[16];
    float* out = (float*)d_out;
    float* ws = (float*)d_ws;

    // float-offset workspace map
    __bf16* aT    = (__bf16*)ws;                  // [0, 1048576)
    __bf16* h1T   = (__bf16*)(ws + 1048576);
    __bf16* cmT   = (__bf16*)(ws + 2097152);      // h2T after attn
    __bf16* cm2   = (__bf16*)(ws + 3145728);
    __bf16* parts = (__bf16*)(ws + 4194304);      // 2 partials
    __bf16* wt    = (__bf16*)(ws + 6291456);
    float*  tembw = ws + 6438912;
    float*  gstat = ws + 6439424;                 // 256 floats
    __bf16* h2T   = cmT;

    prep_kernel<<<dim3(410), dim3(256), 0, stream>>>(
        x, gn1s, gn1b, aT, c1w, c2w, wt, t, mlpw, mlpb, tembw,
        cond, cw, cb, cmT, cm2);
    hipMemsetAsync(gstat, 0, 256 * sizeof(float), stream);
    conv_mfma_kernel<true, false, false><<<dim3(128, BB), dim3(512), 0, stream>>>(
        aT, wt, c1b, tembw, nullptr, h1T, nullptr, nullptr, nullptr, nullptr);
    attn_kernel<<<dim3(WW * BB * NS), dim3(512), 0, stream>>>(h1T, cmT, cm2, parts);
    gn2_stats_kernel<<<dim3(64, BB), dim3(256), 0, stream>>>(h1T, parts, aim, emb, h2T, gstat);
    conv_mfma_kernel<false, true, true><<<dim3(128, BB), dim3(512), 0, stream>>>(
        h2T, wt + (size_t)9 * 16384, c2b, nullptr, x, nullptr, out, gstat, gn2s, gn2b);
}